// Round 6
// baseline (1904.888 us; speedup 1.0000x reference)
//
#include <hip/hip_runtime.h>
#include <math.h>

#define NEGS 0.2f
#define EPSBN 1e-5f
#define NBIN_MAX 256
#define SBITS 9
#define SNODES 512
#define CAP 32

typedef __attribute__((ext_vector_type(8))) short short8v;   // 8 bf16 = 4 VGPR
typedef __attribute__((ext_vector_type(4))) float f32x4;     // MFMA acc

static __device__ __forceinline__ float lrelu(float x){ return x > 0.f ? x : NEGS*x; }
static __device__ __forceinline__ float bf_lo(unsigned u){ return __uint_as_float(u << 16); }
static __device__ __forceinline__ float bf_hi(unsigned u){ return __uint_as_float(u & 0xffff0000u); }
static __device__ __forceinline__ float bf1(unsigned short v){ return __uint_as_float(((unsigned)v) << 16); }
static __device__ __forceinline__ unsigned short f2bf(float f){
  unsigned u = __float_as_uint(f);
  unsigned r = (u + 0x7fff + ((u >> 16) & 1)) >> 16;   // RNE
  return (unsigned short)r;
}

// pad+transpose W2 [40][128] -> Wt2p [128][64] (cols >=40 zero)
__global__ void k_padW2(const float* __restrict__ W2, float* __restrict__ Wt2p){
  int i = blockIdx.x*256 + threadIdx.x;
  if (i >= 128*64) return;
  int k = i >> 6, c = i & 63;
  Wt2p[i] = (c < 40) ? W2[c*128 + k] : 0.f;
}

// ---------------- CSR build: bucketed two-phase ----------------
__global__ void k_bhist(const int* __restrict__ ei, int E, int N, int* __restrict__ bhist){
  int i = blockIdx.x*256 + threadIdx.x;
  int stride = gridDim.x*256;
  int ET = E + N;
  for (; i < ET; i += stride){
    int d = (i < E) ? ei[E + i] : (i - E);
    atomicAdd(&bhist[d >> SBITS], 1);
  }
}

__global__ void k_bscan(const int* __restrict__ bhist, int* __restrict__ bbase,
                        int* __restrict__ gcur, int nb, int* __restrict__ offs,
                        int N, int ET){
  __shared__ int sd[NBIN_MAX];
  int tid = threadIdx.x;
  int v = (tid < nb) ? bhist[tid] : 0;
  sd[tid] = v; __syncthreads();
  for (int off=1; off<NBIN_MAX; off<<=1){
    int t = (tid>=off)? sd[tid-off] : 0;
    __syncthreads();
    sd[tid] += t;
    __syncthreads();
  }
  int excl = sd[tid] - v;
  if (tid < nb){ bbase[tid] = excl; gcur[tid] = excl; }
  if (tid == 0) offs[N] = ET;
}

// LDS-binned scatter of (src,dst) pairs into bucket-contiguous staged[] with
// 128B chunked flushes (full-line writes instead of 1 edge per 64B line).
__global__ __launch_bounds__(256) void k_binscatter(const int* __restrict__ ei, int E, int N,
                        int* __restrict__ gcur, uint2* __restrict__ staged){
  __shared__ uint2 bins[NBIN_MAX][CAP];
  __shared__ int cnt[NBIN_MAX];
  int tid = threadIdx.x;
  cnt[tid] = 0;
  __syncthreads();
  int ET = E + N;
  int chunks = (ET + 255) >> 8;
  int bpg = gridDim.x;
  int c0 = (int)(((long long)chunks * blockIdx.x) / bpg);
  int c1 = (int)(((long long)chunks * (blockIdx.x+1)) / bpg);
  int wv = tid >> 6, l = tid & 63;
  for (int ch = c0; ch < c1; ++ch){
    int i = ch*256 + tid;
    if (i < ET){
      int s, d;
      if (i < E){ s = ei[i]; d = ei[E+i]; } else { s = i-E; d = i-E; }
      int b = d >> SBITS;
      int slot = atomicAdd(&cnt[b], 1);
      uint2 pr = make_uint2((unsigned)s, (unsigned)d);
      if (slot < CAP) bins[b][slot] = pr;
      else staged[atomicAdd(&gcur[b], 1)] = pr;   // rare spill
    }
    __syncthreads();
    for (int b2 = wv; b2 < NBIN_MAX; b2 += 4){
      int resident = min(cnt[b2], CAP);
      int nf = resident >> 4;
      if (nf > 0){
        int base = 0;
        if (l == 0) base = atomicAdd(&gcur[b2], nf*16);
        base = __shfl(base, 0);
        for (int e = l; e < nf*16; e += 64)
          staged[base + e] = bins[b2][e];
        int rem = resident - nf*16;
        if (l < rem) bins[b2][l] = bins[b2][nf*16 + l];
        if (l == 0) cnt[b2] = rem;
      }
    }
    __syncthreads();
  }
  // final flush of remainders (<16 each)
  for (int b2 = wv; b2 < NBIN_MAX; b2 += 4){
    int resident = min(cnt[b2], CAP);
    if (resident > 0){
      int base = 0;
      if (l == 0) base = atomicAdd(&gcur[b2], resident);
      base = __shfl(base, 0);
      if (l < resident) staged[base + l] = bins[b2][l];
    }
  }
}

// one block per bucket: per-node degree + LDS scan -> offs, then scatter csr
// within the bucket's L2-resident window using LDS cursors.
__global__ __launch_bounds__(256) void k_bucket(const uint2* __restrict__ staged,
                         const int* __restrict__ bbase, const int* __restrict__ bhist,
                         int* __restrict__ offs, int* __restrict__ csr, int N){
  __shared__ int sdeg[SNODES];
  __shared__ int sexc[SNODES];
  int b = blockIdx.x, tid = threadIdx.x;
  int node0 = b << SBITS;
  int nn = min(SNODES, N - node0);
  int base = bbase[b], cntb = bhist[b];
  sdeg[2*tid] = 0; sdeg[2*tid+1] = 0;
  __syncthreads();
  for (int e = tid; e < cntb; e += 256){
    uint2 p = staged[base + e];
    atomicAdd(&sdeg[p.y - node0], 1);
  }
  __syncthreads();
  int v0 = sdeg[2*tid], v1 = sdeg[2*tid+1];
  int ps = v0 + v1;
  sexc[tid] = ps; __syncthreads();
  for (int off=1; off<256; off<<=1){
    int t = (tid>=off)? sexc[tid-off] : 0;
    __syncthreads();
    sexc[tid] += t;
    __syncthreads();
  }
  int excl_pair = sexc[tid] - ps;
  __syncthreads();
  sexc[2*tid]   = excl_pair;
  sexc[2*tid+1] = excl_pair + v0;
  if (2*tid   < nn) offs[node0 + 2*tid]   = base + excl_pair;
  if (2*tid+1 < nn) offs[node0 + 2*tid+1] = base + excl_pair + v0;
  sdeg[2*tid] = 0; sdeg[2*tid+1] = 0;
  __syncthreads();
  for (int e = tid; e < cntb; e += 256){
    uint2 p = staged[base + e];
    int ln = p.y - node0;
    int pos = base + sexc[ln] + atomicAdd(&sdeg[ln], 1);
    csr[pos] = (int)p.x;
  }
}

// ------- MFMA GEMM 128x128 (X f32 or bf16 in, bf16 out) + fused logits -------
template<bool BF16IN>
__global__ __launch_bounds__(256) void k_gemm128m(const void* __restrict__ Xin,
                          const float* __restrict__ W,
                          const float* __restrict__ as_, const float* __restrict__ ad_,
                          unsigned short* __restrict__ Yb,
                          float* __restrict__ ALs, float* __restrict__ ALd, int n){
  __shared__ short lds[24576];               // Wb 128x128 @0 (32KB), Xb 64x128 @16384 (16KB)
  unsigned* ldsW = (unsigned*)lds;           // 8192 dwords
  unsigned* ldsX = (unsigned*)(lds + 16384); // 4096 dwords
  int tid = threadIdx.x;
  int r0 = blockIdx.x*64;
  #pragma unroll
  for (int j=0;j<16;++j){
    int i = (256*j + tid)*4;
    int row = i >> 7;
    float4 v = *(const float4*)(W + i);
    int dw = i >> 1, lo = dw & 63, base = dw & ~63;
    int sw = base | (lo ^ ((row&7)<<2));
    uint2 p;
    p.x = (unsigned)f2bf(v.x) | ((unsigned)f2bf(v.y)<<16);
    p.y = (unsigned)f2bf(v.z) | ((unsigned)f2bf(v.w)<<16);
    *(uint2*)(&ldsW[sw]) = p;
  }
  if (!BF16IN){
    const float* X = (const float*)Xin;
    #pragma unroll
    for (int j=0;j<8;++j){
      int i = (256*j + tid)*4;
      int row = i >> 7;
      int grow = r0 + row;
      float4 v = (grow < n) ? *(const float4*)(X + (size_t)grow*128 + (i&127))
                            : make_float4(0.f,0.f,0.f,0.f);
      int dw = i >> 1, lo = dw & 63, base = dw & ~63;
      int sw = base | (lo ^ ((row&7)<<2));
      uint2 p;
      p.x = (unsigned)f2bf(v.x) | ((unsigned)f2bf(v.y)<<16);
      p.y = (unsigned)f2bf(v.z) | ((unsigned)f2bf(v.w)<<16);
      *(uint2*)(&ldsX[sw]) = p;
    }
  } else {
    const unsigned short* Xb = (const unsigned short*)Xin;
    #pragma unroll
    for (int j=0;j<4;++j){
      int dw4 = 1024*j + tid*4;
      int row = dw4 >> 6;
      int grow = r0 + row;
      uint4 v = (grow < n) ? *(const uint4*)(Xb + (size_t)grow*128 + (dw4&63)*2)
                           : make_uint4(0,0,0,0);
      int lo = dw4 & 63, base = dw4 & ~63;
      int sw = base | (lo ^ ((row&7)<<2));
      *(uint4*)(&ldsX[sw]) = v;
    }
  }
  __syncthreads();
  int l = tid & 63, w = tid >> 6;
  int lrow = l & 15, lk = l >> 4;
  int arow = w*16 + lrow;
  int abase = arow*64, ax = (arow&7)<<2;
  short8v a[4];
  #pragma unroll
  for (int ks=0;ks<4;++ks){
    int lo = ks*16 + lk*4;
    a[ks] = *(const short8v*)&ldsX[abase + (lo ^ ax)];
  }
  f32x4 acc[8];
  #pragma unroll
  for (int c=0;c<8;++c) acc[c] = (f32x4){0.f,0.f,0.f,0.f};
  #pragma unroll
  for (int c=0;c<8;++c){
    int brow = c*16 + lrow;
    int bbase2 = brow*64, bx = (brow&7)<<2;
    #pragma unroll
    for (int ks=0;ks<4;++ks){
      int lo = ks*16 + lk*4;
      short8v bfr = *(const short8v*)&ldsW[bbase2 + (lo ^ bx)];
      acc[c] = __builtin_amdgcn_mfma_f32_16x16x32_bf16(a[ks], bfr, acc[c], 0, 0, 0);
    }
  }
  __syncthreads();
  unsigned short* Ys = (unsigned short*)ldsX;
  #pragma unroll
  for (int c=0;c<8;++c){
    #pragma unroll
    for (int r=0;r<4;++r){
      int row = w*16 + lk*4 + r;
      Ys[row*128 + c*16 + lrow] = f2bf(acc[c][r]);
    }
  }
  __syncthreads();
  #pragma unroll
  for (int j=0;j<4;++j){
    int dw4 = 1024*j + tid*4;
    int row = dw4 >> 6;
    int grow = r0 + row;
    if (grow < n)
      *(uint4*)(Yb + (size_t)grow*128 + (dw4&63)*2) = *(const uint4*)&((unsigned*)ldsX)[dw4];
  }
  {
    int row = tid >> 2, h = tid & 3;
    int grow = r0 + row;
    if (grow < n){
      const unsigned short* yr = Ys + row*128 + h*32;
      float ps = 0.f, pd = 0.f;
      #pragma unroll
      for (int j=0;j<32;++j){
        float y = bf1(yr[j]);
        ps = fmaf(y, as_[h*32+j], ps);
        pd = fmaf(y, ad_[h*32+j], pd);
      }
      ALs[grow*4+h] = ps; ALd[grow*4+h] = pd;
    }
  }
}

// ------- fused GAT aggregation + bias + BN + ReLU (bf16 gather, 4 edges/step, prefetch) -------
__global__ __launch_bounds__(256) void k_agg128b(const unsigned short* __restrict__ Pb,
                         const float* __restrict__ ALs, const float* __restrict__ ALd,
                         const int* __restrict__ offs, const int* __restrict__ csr,
                         const float* __restrict__ bias, const float* __restrict__ gam,
                         const float* __restrict__ bet, const float* __restrict__ mean,
                         const float* __restrict__ var, unsigned short* __restrict__ outb, int n){
  int node = blockIdx.x*4 + (threadIdx.x >> 6);
  int lane = threadIdx.x & 63;
  if (node >= n) return;
  int el = lane >> 4, fl = lane & 15, hd = fl >> 2;
  int beg = offs[node], end = offs[node+1];
  int deg = end - beg;
  float aldh = ALd[node*4 + hd];
  int c = (lane < deg) ? csr[beg + lane] : 0;
  float a0=0.f,a1=0.f,a2=0.f,a3=0.f,a4=0.f,a5=0.f,a6=0.f,a7=0.f;
  float wsum = 0.f;
  int nsteps = (deg + 3) >> 2;
  int sCur = __shfl(c, el);
  bool vCur = el < deg;
  uint4 hvCur = *(const uint4*)(Pb + (size_t)sCur*128 + fl*8);
  float alsCur = ALs[sCur*4 + hd];
  for (int t = 0; t < nsteps; ++t){
    int idxN = 4*(t+1) + el;
    int sN = 0; float alsN = 0.f;
    uint4 hvN = make_uint4(0,0,0,0);
    if (t+1 < nsteps){
      sN = (idxN < 64) ? __shfl(c, idxN) : ((idxN < deg) ? csr[beg + idxN] : 0);
      hvN = *(const uint4*)(Pb + (size_t)sN*128 + fl*8);
      alsN = ALs[sN*4 + hd];
    }
    float w = vCur ? __expf(lrelu(alsCur + aldh)) : 0.f;
    wsum += w;
    a0 = fmaf(w, bf_lo(hvCur.x), a0);  a1 = fmaf(w, bf_hi(hvCur.x), a1);
    a2 = fmaf(w, bf_lo(hvCur.y), a2);  a3 = fmaf(w, bf_hi(hvCur.y), a3);
    a4 = fmaf(w, bf_lo(hvCur.z), a4);  a5 = fmaf(w, bf_hi(hvCur.z), a5);
    a6 = fmaf(w, bf_lo(hvCur.w), a6);  a7 = fmaf(w, bf_hi(hvCur.w), a7);
    sCur = sN; hvCur = hvN; alsCur = alsN; vCur = idxN < deg;
  }
  #pragma unroll
  for (int off=16; off<64; off<<=1){
    a0 += __shfl_xor(a0, off); a1 += __shfl_xor(a1, off);
    a2 += __shfl_xor(a2, off); a3 += __shfl_xor(a3, off);
    a4 += __shfl_xor(a4, off); a5 += __shfl_xor(a5, off);
    a6 += __shfl_xor(a6, off); a7 += __shfl_xor(a7, off);
    wsum += __shfl_xor(wsum, off);
  }
  if (el == 0){
    float inv = 1.f / wsum;
    int cc = fl*8;
    float4 bA = *(const float4*)(bias+cc), bB = *(const float4*)(bias+cc+4);
    float4 gA = *(const float4*)(gam+cc),  gB = *(const float4*)(gam+cc+4);
    float4 eA = *(const float4*)(bet+cc),  eB = *(const float4*)(bet+cc+4);
    float4 uA = *(const float4*)(mean+cc), uB = *(const float4*)(mean+cc+4);
    float4 vA = *(const float4*)(var+cc),  vB = *(const float4*)(var+cc+4);
    float o0 = (a0*inv + bA.x - uA.x) * rsqrtf(vA.x + EPSBN) * gA.x + eA.x;
    float o1 = (a1*inv + bA.y - uA.y) * rsqrtf(vA.y + EPSBN) * gA.y + eA.y;
    float o2 = (a2*inv + bA.z - uA.z) * rsqrtf(vA.z + EPSBN) * gA.z + eA.z;
    float o3 = (a3*inv + bA.w - uA.w) * rsqrtf(vA.w + EPSBN) * gA.w + eA.w;
    float o4 = (a4*inv + bB.x - uB.x) * rsqrtf(vB.x + EPSBN) * gB.x + eB.x;
    float o5 = (a5*inv + bB.y - uB.y) * rsqrtf(vB.y + EPSBN) * gB.y + eB.y;
    float o6 = (a6*inv + bB.z - uB.z) * rsqrtf(vB.z + EPSBN) * gB.z + eB.z;
    float o7 = (a7*inv + bB.w - uB.w) * rsqrtf(vB.w + EPSBN) * gB.w + eB.w;
    uint4 q;
    q.x = (unsigned)f2bf(fmaxf(o0,0.f)) | ((unsigned)f2bf(fmaxf(o1,0.f))<<16);
    q.y = (unsigned)f2bf(fmaxf(o2,0.f)) | ((unsigned)f2bf(fmaxf(o3,0.f))<<16);
    q.z = (unsigned)f2bf(fmaxf(o4,0.f)) | ((unsigned)f2bf(fmaxf(o5,0.f))<<16);
    q.w = (unsigned)f2bf(fmaxf(o6,0.f)) | ((unsigned)f2bf(fmaxf(o7,0.f))<<16);
    *(uint4*)(outb + (size_t)node*128 + cc) = q;
  }
}

// ------- output layer GEMM (bf16 in, 128->40 padded 64, bf16 H2 out) + fused logits -------
__global__ __launch_bounds__(256) void k_gemm40n(const unsigned short* __restrict__ Gb,
                                                 const float* __restrict__ Wt2p,
                                                 const float* __restrict__ as2,
                                                 const float* __restrict__ ad2,
                                                 unsigned short* __restrict__ H2b,
                                                 float* __restrict__ al2s,
                                                 float* __restrict__ al2d, int n){
  __shared__ float xt[128*68];   // xt[k*68 + r], r in [0,64)
  int tid = threadIdx.x;
  int r0 = blockIdx.x * 64;
  {
    int r  = tid & 63;
    int c0 = (tid >> 6) * 32;
    int row = r0 + r;
    #pragma unroll
    for (int j=0;j<4;++j){
      uint4 v = (row < n) ? *(const uint4*)(Gb + (size_t)row*128 + c0 + j*8)
                          : make_uint4(0,0,0,0);
      int k = c0 + j*8;
      xt[(k+0)*68 + r] = bf_lo(v.x);  xt[(k+1)*68 + r] = bf_hi(v.x);
      xt[(k+2)*68 + r] = bf_lo(v.y);  xt[(k+3)*68 + r] = bf_hi(v.y);
      xt[(k+4)*68 + r] = bf_lo(v.z);  xt[(k+5)*68 + r] = bf_hi(v.z);
      xt[(k+6)*68 + r] = bf_lo(v.w);  xt[(k+7)*68 + r] = bf_hi(v.w);
    }
  }
  __syncthreads();
  int tc = tid & 15, tr = tid >> 4;
  float acc[4][4] = {};
  #pragma unroll 4
  for (int k=0;k<128;++k){
    float4 wv = *(const float4*)(Wt2p + k*64 + tc*4);
    float4 xv = *(const float4*)(&xt[k*68 + tr*4]);
    float xv4[4] = {xv.x, xv.y, xv.z, xv.w};
    float wv4[4] = {wv.x, wv.y, wv.z, wv.w};
    #pragma unroll
    for (int u=0;u<4;++u)
      #pragma unroll
      for (int v=0;v<4;++v)
        acc[u][v] = fmaf(xv4[u], wv4[v], acc[u][v]);
  }
  float4 a4 = make_float4(0.f,0.f,0.f,0.f), d4 = a4;
  if (tc < 10){
    a4 = *(const float4*)(as2 + tc*4);
    d4 = *(const float4*)(ad2 + tc*4);
  }
  #pragma unroll
  for (int u=0;u<4;++u){
    int row = r0 + tr*4 + u;
    float ps = acc[u][0]*a4.x + acc[u][1]*a4.y + acc[u][2]*a4.z + acc[u][3]*a4.w;
    float pd = acc[u][0]*d4.x + acc[u][1]*d4.y + acc[u][2]*d4.z + acc[u][3]*d4.w;
    #pragma unroll
    for (int m=1; m<16; m<<=1){ ps += __shfl_xor(ps,m); pd += __shfl_xor(pd,m); }
    if (row < n){
      if (tc < 10){
        ushort4 o;
        o.x = f2bf(acc[u][0]); o.y = f2bf(acc[u][1]);
        o.z = f2bf(acc[u][2]); o.w = f2bf(acc[u][3]);
        *(ushort4*)(H2b + (size_t)row*40 + tc*4) = o;
      }
      if (tc == 0){ al2s[row] = ps; al2d[row] = pd; }
    }
  }
}

// ------- output aggregation + bias + log_softmax (bf16 gather, 8 edges/step, prefetch) -------
__global__ __launch_bounds__(256) void k_agg40b(const unsigned short* __restrict__ H2b,
                        const float* __restrict__ ALs, const float* __restrict__ ALd,
                        const int* __restrict__ offs, const int* __restrict__ csr,
                        const float* __restrict__ b2, float* __restrict__ out, int n){
  int node = blockIdx.x*4 + (threadIdx.x >> 6);
  int lane = threadIdx.x & 63;
  if (node >= n) return;
  int el = lane >> 3, fl = lane & 7;
  bool act = fl < 5;
  int beg = offs[node], end = offs[node+1];
  int deg = end - beg;
  float ald = ALd[node];
  int c = (lane < deg) ? csr[beg + lane] : 0;
  float a0=0.f,a1=0.f,a2=0.f,a3=0.f,a4=0.f,a5=0.f,a6=0.f,a7=0.f;
  float wsum = 0.f;
  int nsteps = (deg + 7) >> 3;
  int sCur = __shfl(c, el);
  bool vCur = el < deg;
  uint4 hvCur = act ? *(const uint4*)(H2b + (size_t)sCur*40 + fl*8) : make_uint4(0,0,0,0);
  float alsCur = ALs[sCur];
  for (int t = 0; t < nsteps; ++t){
    int idxN = 8*(t+1) + el;
    int sN = 0; float alsN = 0.f;
    uint4 hvN = make_uint4(0,0,0,0);
    if (t+1 < nsteps){
      sN = (idxN < 64) ? __shfl(c, idxN) : ((idxN < deg) ? csr[beg + idxN] : 0);
      if (act) hvN = *(const uint4*)(H2b + (size_t)sN*40 + fl*8);
      alsN = ALs[sN];
    }
    float w = vCur ? __expf(lrelu(alsCur + ald)) : 0.f;
    wsum += w;
    a0 = fmaf(w, bf_lo(hvCur.x), a0);  a1 = fmaf(w, bf_hi(hvCur.x), a1);
    a2 = fmaf(w, bf_lo(hvCur.y), a2);  a3 = fmaf(w, bf_hi(hvCur.y), a3);
    a4 = fmaf(w, bf_lo(hvCur.z), a4);  a5 = fmaf(w, bf_hi(hvCur.z), a5);
    a6 = fmaf(w, bf_lo(hvCur.w), a6);  a7 = fmaf(w, bf_hi(hvCur.w), a7);
    sCur = sN; hvCur = hvN; alsCur = alsN; vCur = idxN < deg;
  }
  #pragma unroll
  for (int off=8; off<64; off<<=1){
    a0 += __shfl_xor(a0, off); a1 += __shfl_xor(a1, off);
    a2 += __shfl_xor(a2, off); a3 += __shfl_xor(a3, off);
    a4 += __shfl_xor(a4, off); a5 += __shfl_xor(a5, off);
    a6 += __shfl_xor(a6, off); a7 += __shfl_xor(a7, off);
    wsum += __shfl_xor(wsum, off);
  }
  if (el == 0){
    float inv = 1.f / wsum;
    float y0=0.f,y1=0.f,y2=0.f,y3=0.f,y4=0.f,y5=0.f,y6=0.f,y7=0.f;
    if (act){
      int cc = fl*8;
      float4 bA = *(const float4*)(b2 + cc), bB = *(const float4*)(b2 + cc + 4);
      y0 = a0*inv + bA.x; y1 = a1*inv + bA.y; y2 = a2*inv + bA.z; y3 = a3*inv + bA.w;
      y4 = a4*inv + bB.x; y5 = a5*inv + bB.y; y6 = a6*inv + bB.z; y7 = a7*inv + bB.w;
    }
    float lm = act ? fmaxf(fmaxf(fmaxf(y0,y1),fmaxf(y2,y3)),
                           fmaxf(fmaxf(y4,y5),fmaxf(y6,y7))) : -1e30f;
    lm = fmaxf(lm, __shfl_xor(lm,1));
    lm = fmaxf(lm, __shfl_xor(lm,2));
    lm = fmaxf(lm, __shfl_xor(lm,4));
    float ls = act ? (__expf(y0-lm)+__expf(y1-lm)+__expf(y2-lm)+__expf(y3-lm)
                     +__expf(y4-lm)+__expf(y5-lm)+__expf(y6-lm)+__expf(y7-lm)) : 0.f;
    ls += __shfl_xor(ls,1);
    ls += __shfl_xor(ls,2);
    ls += __shfl_xor(ls,4);
    float lg = lm + __logf(ls);
    if (act){
      float4* dst = (float4*)(out + (size_t)node*40 + fl*8);
      dst[0] = make_float4(y0-lg, y1-lg, y2-lg, y3-lg);
      dst[1] = make_float4(y4-lg, y5-lg, y6-lg, y7-lg);
    }
  }
}

extern "C" void kernel_launch(void* const* d_in, const int* in_sizes, int n_in,
                              void* d_out, int out_size, void* d_ws, size_t ws_size,
                              hipStream_t stream) {
  const float* x   = (const float*)d_in[0];
  const int*   ei  = (const int*)d_in[1];
  const float* W0  = (const float*)d_in[2];
  const float* as0 = (const float*)d_in[3];
  const float* ad0 = (const float*)d_in[4];
  const float* b0  = (const float*)d_in[5];
  const float* g0  = (const float*)d_in[6];
  const float* be0 = (const float*)d_in[7];
  const float* m0  = (const float*)d_in[8];
  const float* v0  = (const float*)d_in[9];
  const float* W1  = (const float*)d_in[10];
  const float* as1 = (const float*)d_in[11];
  const float* ad1 = (const float*)d_in[12];
  const float* b1  = (const float*)d_in[13];
  const float* g1  = (const float*)d_in[14];
  const float* be1 = (const float*)d_in[15];
  const float* m1  = (const float*)d_in[16];
  const float* v1  = (const float*)d_in[17];
  const float* W2  = (const float*)d_in[18];
  const float* as2 = (const float*)d_in[19];
  const float* ad2 = (const float*)d_in[20];
  const float* b2  = (const float*)d_in[21];
  float* out = (float*)d_out;

  int N = in_sizes[0] / 128;
  int E = in_sizes[1] / 2;
  int ET = E + N;
  int NBIN = (N + SNODES - 1) >> SBITS;   // 196 for N=100000 (<= NBIN_MAX)

  char* p = (char*)d_ws;
  auto alloc = [&](size_t bytes)->void* {
    void* r = (void*)p;
    p += (bytes + 255) & ~size_t(255);
    return r;
  };
  float* Wt2p  = (float*)alloc((size_t)128*64*4);
  int* bhist   = (int*)alloc((size_t)NBIN_MAX*4);
  int* bbase   = (int*)alloc((size_t)NBIN_MAX*4);
  int* gcur    = (int*)alloc((size_t)NBIN_MAX*4);
  int* offs    = (int*)alloc((size_t)(N+1)*4);
  int* csr     = (int*)alloc((size_t)ET*4);
  uint2* staged= (uint2*)alloc((size_t)ET*8);
  unsigned short* Pb = (unsigned short*)alloc((size_t)N*128*2);
  unsigned short* Gb = (unsigned short*)alloc((size_t)N*128*2);
  float* ALs = (float*)alloc((size_t)N*4*4);
  float* ALd = (float*)alloc((size_t)N*4*4);
  unsigned short* H2b = Pb;     // Pb free by the time layer-2 GEMM runs
  float* al2s = ALs;
  float* al2d = ALd;
  if ((size_t)(p - (char*)d_ws) > ws_size) return;  // workspace too small

  hipMemsetAsync(bhist, 0, NBIN_MAX*4, stream);

  // weight prep (only W2 needs transpose+pad; W0/W1 feed MFMA as-is)
  k_padW2<<<(128*64+255)/256, 256, 0, stream>>>(W2, Wt2p);

  // CSR build (bucketed two-phase)
  k_bhist<<<512, 256, 0, stream>>>(ei, E, N, bhist);
  k_bscan<<<1, NBIN_MAX, 0, stream>>>(bhist, bbase, gcur, NBIN, offs, N, ET);
  k_binscatter<<<256, 256, 0, stream>>>(ei, E, N, gcur, staged);
  k_bucket<<<NBIN, 256, 0, stream>>>(staged, bbase, bhist, offs, csr, N);

  int gb = (N + 63) / 64;
  // ---- layer 0 ----
  k_gemm128m<false><<<gb, 256, 0, stream>>>(x, W0, as0, ad0, Pb, ALs, ALd, N);
  k_agg128b<<<(N+3)/4, 256, 0, stream>>>(Pb, ALs, ALd, offs, csr, b0, g0, be0, m0, v0, Gb, N);

  // ---- layer 1 ----
  k_gemm128m<true><<<gb, 256, 0, stream>>>(Gb, W1, as1, ad1, Pb, ALs, ALd, N);
  k_agg128b<<<(N+3)/4, 256, 0, stream>>>(Pb, ALs, ALd, offs, csr, b1, g1, be1, m1, v1, Gb, N);

  // ---- output layer ----
  k_gemm40n<<<gb, 256, 0, stream>>>(Gb, Wt2p, as2, ad2, H2b, al2s, al2d, N);
  k_agg40b<<<(N+3)/4, 256, 0, stream>>>(H2b, al2s, al2d, offs, csr, b2, out, N);
}

// Round 7
// 551.608 us; speedup vs baseline: 3.4533x; 3.4533x over previous
//
#include <hip/hip_runtime.h>
#include <math.h>

#define NEGS 0.2f
#define EPSBN 1e-5f
#define NBIN_MAX 256
#define SBITS 9
#define SNODES 512
#define GLH 256   // blocks for lhist/write

typedef __attribute__((ext_vector_type(8))) short short8v;   // 8 bf16 = 4 VGPR
typedef __attribute__((ext_vector_type(4))) float f32x4;     // MFMA acc

static __device__ __forceinline__ float lrelu(float x){ return x > 0.f ? x : NEGS*x; }
static __device__ __forceinline__ float bf_lo(unsigned u){ return __uint_as_float(u << 16); }
static __device__ __forceinline__ float bf_hi(unsigned u){ return __uint_as_float(u & 0xffff0000u); }
static __device__ __forceinline__ float bf1(unsigned short v){ return __uint_as_float(((unsigned)v) << 16); }
static __device__ __forceinline__ unsigned short f2bf(float f){
  unsigned u = __float_as_uint(f);
  unsigned r = (u + 0x7fff + ((u >> 16) & 1)) >> 16;   // RNE
  return (unsigned short)r;
}

// pad+transpose W2 [40][128] -> Wt2p [128][64] (cols >=40 zero)
__global__ void k_padW2(const float* __restrict__ W2, float* __restrict__ Wt2p){
  int i = blockIdx.x*256 + threadIdx.x;
  if (i >= 128*64) return;
  int k = i >> 6, c = i & 63;
  Wt2p[i] = (c < 40) ? W2[c*128 + k] : 0.f;
}

// ---------------- per-node degree (atomics over 100K addresses: fine) ----------------
__global__ void k_deg(const int* __restrict__ ei, int E, int N, int* __restrict__ deg){
  int i = blockIdx.x*256 + threadIdx.x;
  if (i >= E + N) return;
  int d = (i < E) ? ei[E + i] : (i - E);
  atomicAdd(&deg[d], 1);
}

// generic 3-kernel exclusive scan: scan1 writes inclusive into out[i+1]
__global__ void k_scan1(const int* __restrict__ deg, int* __restrict__ incl,
                        int* __restrict__ partials, int n){
  __shared__ int sd[256];
  int tid = threadIdx.x;
  int base = blockIdx.x*1024 + tid*4;
  int v[4]; int s = 0;
  #pragma unroll
  for (int j=0;j<4;++j){ int idx = base+j; v[j] = (idx<n)? deg[idx] : 0; s += v[j]; }
  sd[tid] = s; __syncthreads();
  for (int off=1; off<256; off<<=1){
    int t = (tid>=off)? sd[tid-off] : 0;
    __syncthreads();
    sd[tid] += t;
    __syncthreads();
  }
  int run = sd[tid] - s;
  #pragma unroll
  for (int j=0;j<4;++j){ int idx = base+j; run += v[j]; if (idx<n) incl[idx] = run; }
  if (tid==255) partials[blockIdx.x] = sd[255];
}

__global__ void k_scan2(int* partials, int nb){
  __shared__ int sd[256];
  int tid = threadIdx.x;
  sd[tid] = (tid<nb)? partials[tid] : 0;
  __syncthreads();
  for (int off=1; off<256; off<<=1){
    int t = (tid>=off)? sd[tid-off] : 0;
    __syncthreads();
    sd[tid] += t;
    __syncthreads();
  }
  if (tid<nb) partials[tid] = sd[tid];
}

__global__ void k_scan3(int* __restrict__ offs, const int* __restrict__ partials, int n){
  int i = blockIdx.x*256 + threadIdx.x;
  if (i == 0) offs[0] = 0;
  if (i >= n) return;
  int b = i >> 10;
  if (b > 0) offs[i+1] += partials[b-1];
}

// ---------------- bucket-sort staging (contention-free) ----------------
// block-local LDS histogram over buckets -> Hmat[bin*GLH + block]
__global__ __launch_bounds__(256) void k_lhist(const int* __restrict__ ei, int E, int N,
                                               int* __restrict__ Hmat, int nbin){
  __shared__ int lh[NBIN_MAX];
  int tid = threadIdx.x;
  lh[tid] = 0;
  __syncthreads();
  int ET = E + N;
  int c0 = (int)(((long long)ET * blockIdx.x) / GLH);
  int c1 = (int)(((long long)ET * (blockIdx.x+1)) / GLH);
  for (int i = c0 + tid; i < c1; i += 256){
    int d = (i < E) ? ei[E + i] : (i - E);
    atomicAdd(&lh[d >> SBITS], 1);
  }
  __syncthreads();
  for (int b = tid; b < nbin; b += 256)
    Hmat[b*GLH + blockIdx.x] = lh[b];
}

// re-read edges, write (src,dst) into disjoint staged ranges (LDS cursors, no global atomics)
__global__ __launch_bounds__(256) void k_write(const int* __restrict__ ei, int E, int N,
                        const int* __restrict__ Bmat, uint2* __restrict__ staged, int nbin){
  __shared__ int cur[NBIN_MAX];
  int tid = threadIdx.x;
  for (int b = tid; b < nbin; b += 256)
    cur[b] = Bmat[b*GLH + blockIdx.x];
  __syncthreads();
  int ET = E + N;
  int c0 = (int)(((long long)ET * blockIdx.x) / GLH);
  int c1 = (int)(((long long)ET * (blockIdx.x+1)) / GLH);
  for (int i = c0 + tid; i < c1; i += 256){
    int s, d;
    if (i < E){ s = ei[i]; d = ei[E+i]; } else { s = i-E; d = i-E; }
    int pos = atomicAdd(&cur[d >> SBITS], 1);
    staged[pos] = make_uint2((unsigned)s, (unsigned)d);
  }
}

// one block per bucket: scatter staged -> csr within L2-resident window (LDS node cursors)
__global__ __launch_bounds__(256) void k_bucket2(const uint2* __restrict__ staged,
                         const int* __restrict__ offs, int* __restrict__ csr, int N){
  __shared__ int scur[SNODES];
  int b = blockIdx.x, tid = threadIdx.x;
  int node0 = b << SBITS;
  int nn = min(SNODES, N - node0);
  if (tid < nn) scur[tid] = offs[node0 + tid];
  if (tid + 256 < nn) scur[tid + 256] = offs[node0 + tid + 256];
  __syncthreads();
  int base = offs[node0];
  int endp = offs[node0 + nn];
  for (int e = base + tid; e < endp; e += 256){
    uint2 p = staged[e];
    int pos = atomicAdd(&scur[p.y - node0], 1);
    csr[pos] = (int)p.x;
  }
}

// ------- MFMA GEMM 128x128 (X f32 or bf16 in, bf16 out) + fused logits -------
template<bool BF16IN>
__global__ __launch_bounds__(256) void k_gemm128m(const void* __restrict__ Xin,
                          const float* __restrict__ W,
                          const float* __restrict__ as_, const float* __restrict__ ad_,
                          unsigned short* __restrict__ Yb,
                          float* __restrict__ ALs, float* __restrict__ ALd, int n){
  __shared__ short lds[24576];               // Wb 128x128 @0 (32KB), Xb 64x128 @16384 (16KB)
  unsigned* ldsW = (unsigned*)lds;           // 8192 dwords
  unsigned* ldsX = (unsigned*)(lds + 16384); // 4096 dwords
  int tid = threadIdx.x;
  int r0 = blockIdx.x*64;
  #pragma unroll
  for (int j=0;j<16;++j){
    int i = (256*j + tid)*4;
    int row = i >> 7;
    float4 v = *(const float4*)(W + i);
    int dw = i >> 1, lo = dw & 63, base = dw & ~63;
    int sw = base | (lo ^ ((row&7)<<2));
    uint2 p;
    p.x = (unsigned)f2bf(v.x) | ((unsigned)f2bf(v.y)<<16);
    p.y = (unsigned)f2bf(v.z) | ((unsigned)f2bf(v.w)<<16);
    *(uint2*)(&ldsW[sw]) = p;
  }
  if (!BF16IN){
    const float* X = (const float*)Xin;
    #pragma unroll
    for (int j=0;j<8;++j){
      int i = (256*j + tid)*4;
      int row = i >> 7;
      int grow = r0 + row;
      float4 v = (grow < n) ? *(const float4*)(X + (size_t)grow*128 + (i&127))
                            : make_float4(0.f,0.f,0.f,0.f);
      int dw = i >> 1, lo = dw & 63, base = dw & ~63;
      int sw = base | (lo ^ ((row&7)<<2));
      uint2 p;
      p.x = (unsigned)f2bf(v.x) | ((unsigned)f2bf(v.y)<<16);
      p.y = (unsigned)f2bf(v.z) | ((unsigned)f2bf(v.w)<<16);
      *(uint2*)(&ldsX[sw]) = p;
    }
  } else {
    const unsigned short* Xb = (const unsigned short*)Xin;
    #pragma unroll
    for (int j=0;j<4;++j){
      int dw4 = 1024*j + tid*4;
      int row = dw4 >> 6;
      int grow = r0 + row;
      uint4 v = (grow < n) ? *(const uint4*)(Xb + (size_t)grow*128 + (dw4&63)*2)
                           : make_uint4(0,0,0,0);
      int lo = dw4 & 63, base = dw4 & ~63;
      int sw = base | (lo ^ ((row&7)<<2));
      *(uint4*)(&ldsX[sw]) = v;
    }
  }
  __syncthreads();
  int l = tid & 63, w = tid >> 6;
  int lrow = l & 15, lk = l >> 4;
  int arow = w*16 + lrow;
  int abase = arow*64, ax = (arow&7)<<2;
  short8v a[4];
  #pragma unroll
  for (int ks=0;ks<4;++ks){
    int lo = ks*16 + lk*4;
    a[ks] = *(const short8v*)&ldsX[abase + (lo ^ ax)];
  }
  f32x4 acc[8];
  #pragma unroll
  for (int c=0;c<8;++c) acc[c] = (f32x4){0.f,0.f,0.f,0.f};
  #pragma unroll
  for (int c=0;c<8;++c){
    int brow = c*16 + lrow;
    int bbase2 = brow*64, bx = (brow&7)<<2;
    #pragma unroll
    for (int ks=0;ks<4;++ks){
      int lo = ks*16 + lk*4;
      short8v bfr = *(const short8v*)&ldsW[bbase2 + (lo ^ bx)];
      acc[c] = __builtin_amdgcn_mfma_f32_16x16x32_bf16(a[ks], bfr, acc[c], 0, 0, 0);
    }
  }
  __syncthreads();
  unsigned short* Ys = (unsigned short*)ldsX;
  #pragma unroll
  for (int c=0;c<8;++c){
    #pragma unroll
    for (int r=0;r<4;++r){
      int row = w*16 + lk*4 + r;
      Ys[row*128 + c*16 + lrow] = f2bf(acc[c][r]);
    }
  }
  __syncthreads();
  #pragma unroll
  for (int j=0;j<4;++j){
    int dw4 = 1024*j + tid*4;
    int row = dw4 >> 6;
    int grow = r0 + row;
    if (grow < n)
      *(uint4*)(Yb + (size_t)grow*128 + (dw4&63)*2) = *(const uint4*)&((unsigned*)ldsX)[dw4];
  }
  {
    int row = tid >> 2, h = tid & 3;
    int grow = r0 + row;
    if (grow < n){
      const unsigned short* yr = Ys + row*128 + h*32;
      float ps = 0.f, pd = 0.f;
      #pragma unroll
      for (int j=0;j<32;++j){
        float y = bf1(yr[j]);
        ps = fmaf(y, as_[h*32+j], ps);
        pd = fmaf(y, ad_[h*32+j], pd);
      }
      ALs[grow*4+h] = ps; ALd[grow*4+h] = pd;
    }
  }
}

// ------- fused GAT aggregation + bias + BN + ReLU (bf16 gather, 4 edges/step, prefetch) -------
__global__ __launch_bounds__(256) void k_agg128b(const unsigned short* __restrict__ Pb,
                         const float* __restrict__ ALs, const float* __restrict__ ALd,
                         const int* __restrict__ offs, const int* __restrict__ csr,
                         const float* __restrict__ bias, const float* __restrict__ gam,
                         const float* __restrict__ bet, const float* __restrict__ mean,
                         const float* __restrict__ var, unsigned short* __restrict__ outb, int n){
  int node = blockIdx.x*4 + (threadIdx.x >> 6);
  int lane = threadIdx.x & 63;
  if (node >= n) return;
  int el = lane >> 4, fl = lane & 15, hd = fl >> 2;
  int beg = offs[node], end = offs[node+1];
  int deg = end - beg;
  float aldh = ALd[node*4 + hd];
  int c = (lane < deg) ? csr[beg + lane] : 0;
  float a0=0.f,a1=0.f,a2=0.f,a3=0.f,a4=0.f,a5=0.f,a6=0.f,a7=0.f;
  float wsum = 0.f;
  int nsteps = (deg + 3) >> 2;
  int sCur = __shfl(c, el);
  bool vCur = el < deg;
  uint4 hvCur = *(const uint4*)(Pb + (size_t)sCur*128 + fl*8);
  float alsCur = ALs[sCur*4 + hd];
  for (int t = 0; t < nsteps; ++t){
    int idxN = 4*(t+1) + el;
    int sN = 0; float alsN = 0.f;
    uint4 hvN = make_uint4(0,0,0,0);
    if (t+1 < nsteps){
      sN = (idxN < 64) ? __shfl(c, idxN) : ((idxN < deg) ? csr[beg + idxN] : 0);
      hvN = *(const uint4*)(Pb + (size_t)sN*128 + fl*8);
      alsN = ALs[sN*4 + hd];
    }
    float w = vCur ? __expf(lrelu(alsCur + aldh)) : 0.f;
    wsum += w;
    a0 = fmaf(w, bf_lo(hvCur.x), a0);  a1 = fmaf(w, bf_hi(hvCur.x), a1);
    a2 = fmaf(w, bf_lo(hvCur.y), a2);  a3 = fmaf(w, bf_hi(hvCur.y), a3);
    a4 = fmaf(w, bf_lo(hvCur.z), a4);  a5 = fmaf(w, bf_hi(hvCur.z), a5);
    a6 = fmaf(w, bf_lo(hvCur.w), a6);  a7 = fmaf(w, bf_hi(hvCur.w), a7);
    sCur = sN; hvCur = hvN; alsCur = alsN; vCur = idxN < deg;
  }
  #pragma unroll
  for (int off=16; off<64; off<<=1){
    a0 += __shfl_xor(a0, off); a1 += __shfl_xor(a1, off);
    a2 += __shfl_xor(a2, off); a3 += __shfl_xor(a3, off);
    a4 += __shfl_xor(a4, off); a5 += __shfl_xor(a5, off);
    a6 += __shfl_xor(a6, off); a7 += __shfl_xor(a7, off);
    wsum += __shfl_xor(wsum, off);
  }
  if (el == 0){
    float inv = 1.f / wsum;
    int cc = fl*8;
    float4 bA = *(const float4*)(bias+cc), bB = *(const float4*)(bias+cc+4);
    float4 gA = *(const float4*)(gam+cc),  gB = *(const float4*)(gam+cc+4);
    float4 eA = *(const float4*)(bet+cc),  eB = *(const float4*)(bet+cc+4);
    float4 uA = *(const float4*)(mean+cc), uB = *(const float4*)(mean+cc+4);
    float4 vA = *(const float4*)(var+cc),  vB = *(const float4*)(var+cc+4);
    float o0 = (a0*inv + bA.x - uA.x) * rsqrtf(vA.x + EPSBN) * gA.x + eA.x;
    float o1 = (a1*inv + bA.y - uA.y) * rsqrtf(vA.y + EPSBN) * gA.y + eA.y;
    float o2 = (a2*inv + bA.z - uA.z) * rsqrtf(vA.z + EPSBN) * gA.z + eA.z;
    float o3 = (a3*inv + bA.w - uA.w) * rsqrtf(vA.w + EPSBN) * gA.w + eA.w;
    float o4 = (a4*inv + bB.x - uB.x) * rsqrtf(vB.x + EPSBN) * gB.x + eB.x;
    float o5 = (a5*inv + bB.y - uB.y) * rsqrtf(vB.y + EPSBN) * gB.y + eB.y;
    float o6 = (a6*inv + bB.z - uB.z) * rsqrtf(vB.z + EPSBN) * gB.z + eB.z;
    float o7 = (a7*inv + bB.w - uB.w) * rsqrtf(vB.w + EPSBN) * gB.w + eB.w;
    uint4 q;
    q.x = (unsigned)f2bf(fmaxf(o0,0.f)) | ((unsigned)f2bf(fmaxf(o1,0.f))<<16);
    q.y = (unsigned)f2bf(fmaxf(o2,0.f)) | ((unsigned)f2bf(fmaxf(o3,0.f))<<16);
    q.z = (unsigned)f2bf(fmaxf(o4,0.f)) | ((unsigned)f2bf(fmaxf(o5,0.f))<<16);
    q.w = (unsigned)f2bf(fmaxf(o6,0.f)) | ((unsigned)f2bf(fmaxf(o7,0.f))<<16);
    *(uint4*)(outb + (size_t)node*128 + cc) = q;
  }
}

// ------- output layer GEMM (bf16 in, 128->40 padded 64, bf16 H2 out) + fused logits -------
__global__ __launch_bounds__(256) void k_gemm40n(const unsigned short* __restrict__ Gb,
                                                 const float* __restrict__ Wt2p,
                                                 const float* __restrict__ as2,
                                                 const float* __restrict__ ad2,
                                                 unsigned short* __restrict__ H2b,
                                                 float* __restrict__ al2s,
                                                 float* __restrict__ al2d, int n){
  __shared__ float xt[128*68];   // xt[k*68 + r], r in [0,64)
  int tid = threadIdx.x;
  int r0 = blockIdx.x * 64;
  {
    int r  = tid & 63;
    int c0 = (tid >> 6) * 32;
    int row = r0 + r;
    #pragma unroll
    for (int j=0;j<4;++j){
      uint4 v = (row < n) ? *(const uint4*)(Gb + (size_t)row*128 + c0 + j*8)
                          : make_uint4(0,0,0,0);
      int k = c0 + j*8;
      xt[(k+0)*68 + r] = bf_lo(v.x);  xt[(k+1)*68 + r] = bf_hi(v.x);
      xt[(k+2)*68 + r] = bf_lo(v.y);  xt[(k+3)*68 + r] = bf_hi(v.y);
      xt[(k+4)*68 + r] = bf_lo(v.z);  xt[(k+5)*68 + r] = bf_hi(v.z);
      xt[(k+6)*68 + r] = bf_lo(v.w);  xt[(k+7)*68 + r] = bf_hi(v.w);
    }
  }
  __syncthreads();
  int tc = tid & 15, tr = tid >> 4;
  float acc[4][4] = {};
  #pragma unroll 4
  for (int k=0;k<128;++k){
    float4 wv = *(const float4*)(Wt2p + k*64 + tc*4);
    float4 xv = *(const float4*)(&xt[k*68 + tr*4]);
    float xv4[4] = {xv.x, xv.y, xv.z, xv.w};
    float wv4[4] = {wv.x, wv.y, wv.z, wv.w};
    #pragma unroll
    for (int u=0;u<4;++u)
      #pragma unroll
      for (int v=0;v<4;++v)
        acc[u][v] = fmaf(xv4[u], wv4[v], acc[u][v]);
  }
  float4 a4 = make_float4(0.f,0.f,0.f,0.f), d4 = a4;
  if (tc < 10){
    a4 = *(const float4*)(as2 + tc*4);
    d4 = *(const float4*)(ad2 + tc*4);
  }
  #pragma unroll
  for (int u=0;u<4;++u){
    int row = r0 + tr*4 + u;
    float ps = acc[u][0]*a4.x + acc[u][1]*a4.y + acc[u][2]*a4.z + acc[u][3]*a4.w;
    float pd = acc[u][0]*d4.x + acc[u][1]*d4.y + acc[u][2]*d4.z + acc[u][3]*d4.w;
    #pragma unroll
    for (int m=1; m<16; m<<=1){ ps += __shfl_xor(ps,m); pd += __shfl_xor(pd,m); }
    if (row < n){
      if (tc < 10){
        ushort4 o;
        o.x = f2bf(acc[u][0]); o.y = f2bf(acc[u][1]);
        o.z = f2bf(acc[u][2]); o.w = f2bf(acc[u][3]);
        *(ushort4*)(H2b + (size_t)row*40 + tc*4) = o;
      }
      if (tc == 0){ al2s[row] = ps; al2d[row] = pd; }
    }
  }
}

// ------- output aggregation + bias + log_softmax (bf16 gather, 8 edges/step, prefetch) -------
__global__ __launch_bounds__(256) void k_agg40b(const unsigned short* __restrict__ H2b,
                        const float* __restrict__ ALs, const float* __restrict__ ALd,
                        const int* __restrict__ offs, const int* __restrict__ csr,
                        const float* __restrict__ b2, float* __restrict__ out, int n){
  int node = blockIdx.x*4 + (threadIdx.x >> 6);
  int lane = threadIdx.x & 63;
  if (node >= n) return;
  int el = lane >> 3, fl = lane & 7;
  bool act = fl < 5;
  int beg = offs[node], end = offs[node+1];
  int deg = end - beg;
  float ald = ALd[node];
  int c = (lane < deg) ? csr[beg + lane] : 0;
  float a0=0.f,a1=0.f,a2=0.f,a3=0.f,a4=0.f,a5=0.f,a6=0.f,a7=0.f;
  float wsum = 0.f;
  int nsteps = (deg + 7) >> 3;
  int sCur = __shfl(c, el);
  bool vCur = el < deg;
  uint4 hvCur = act ? *(const uint4*)(H2b + (size_t)sCur*40 + fl*8) : make_uint4(0,0,0,0);
  float alsCur = ALs[sCur];
  for (int t = 0; t < nsteps; ++t){
    int idxN = 8*(t+1) + el;
    int sN = 0; float alsN = 0.f;
    uint4 hvN = make_uint4(0,0,0,0);
    if (t+1 < nsteps){
      sN = (idxN < 64) ? __shfl(c, idxN) : ((idxN < deg) ? csr[beg + idxN] : 0);
      if (act) hvN = *(const uint4*)(H2b + (size_t)sN*40 + fl*8);
      alsN = ALs[sN];
    }
    float w = vCur ? __expf(lrelu(alsCur + ald)) : 0.f;
    wsum += w;
    a0 = fmaf(w, bf_lo(hvCur.x), a0);  a1 = fmaf(w, bf_hi(hvCur.x), a1);
    a2 = fmaf(w, bf_lo(hvCur.y), a2);  a3 = fmaf(w, bf_hi(hvCur.y), a3);
    a4 = fmaf(w, bf_lo(hvCur.z), a4);  a5 = fmaf(w, bf_hi(hvCur.z), a5);
    a6 = fmaf(w, bf_lo(hvCur.w), a6);  a7 = fmaf(w, bf_hi(hvCur.w), a7);
    sCur = sN; hvCur = hvN; alsCur = alsN; vCur = idxN < deg;
  }
  #pragma unroll
  for (int off=8; off<64; off<<=1){
    a0 += __shfl_xor(a0, off); a1 += __shfl_xor(a1, off);
    a2 += __shfl_xor(a2, off); a3 += __shfl_xor(a3, off);
    a4 += __shfl_xor(a4, off); a5 += __shfl_xor(a5, off);
    a6 += __shfl_xor(a6, off); a7 += __shfl_xor(a7, off);
    wsum += __shfl_xor(wsum, off);
  }
  if (el == 0){
    float inv = 1.f / wsum;
    float y0=0.f,y1=0.f,y2=0.f,y3=0.f,y4=0.f,y5=0.f,y6=0.f,y7=0.f;
    if (act){
      int cc = fl*8;
      float4 bA = *(const float4*)(b2 + cc), bB = *(const float4*)(b2 + cc + 4);
      y0 = a0*inv + bA.x; y1 = a1*inv + bA.y; y2 = a2*inv + bA.z; y3 = a3*inv + bA.w;
      y4 = a4*inv + bB.x; y5 = a5*inv + bB.y; y6 = a6*inv + bB.z; y7 = a7*inv + bB.w;
    }
    float lm = act ? fmaxf(fmaxf(fmaxf(y0,y1),fmaxf(y2,y3)),
                           fmaxf(fmaxf(y4,y5),fmaxf(y6,y7))) : -1e30f;
    lm = fmaxf(lm, __shfl_xor(lm,1));
    lm = fmaxf(lm, __shfl_xor(lm,2));
    lm = fmaxf(lm, __shfl_xor(lm,4));
    float ls = act ? (__expf(y0-lm)+__expf(y1-lm)+__expf(y2-lm)+__expf(y3-lm)
                     +__expf(y4-lm)+__expf(y5-lm)+__expf(y6-lm)+__expf(y7-lm)) : 0.f;
    ls += __shfl_xor(ls,1);
    ls += __shfl_xor(ls,2);
    ls += __shfl_xor(ls,4);
    float lg = lm + __logf(ls);
    if (act){
      float4* dst = (float4*)(out + (size_t)node*40 + fl*8);
      dst[0] = make_float4(y0-lg, y1-lg, y2-lg, y3-lg);
      dst[1] = make_float4(y4-lg, y5-lg, y6-lg, y7-lg);
    }
  }
}

extern "C" void kernel_launch(void* const* d_in, const int* in_sizes, int n_in,
                              void* d_out, int out_size, void* d_ws, size_t ws_size,
                              hipStream_t stream) {
  const float* x   = (const float*)d_in[0];
  const int*   ei  = (const int*)d_in[1];
  const float* W0  = (const float*)d_in[2];
  const float* as0 = (const float*)d_in[3];
  const float* ad0 = (const float*)d_in[4];
  const float* b0  = (const float*)d_in[5];
  const float* g0  = (const float*)d_in[6];
  const float* be0 = (const float*)d_in[7];
  const float* m0  = (const float*)d_in[8];
  const float* v0  = (const float*)d_in[9];
  const float* W1  = (const float*)d_in[10];
  const float* as1 = (const float*)d_in[11];
  const float* ad1 = (const float*)d_in[12];
  const float* b1  = (const float*)d_in[13];
  const float* g1  = (const float*)d_in[14];
  const float* be1 = (const float*)d_in[15];
  const float* m1  = (const float*)d_in[16];
  const float* v1  = (const float*)d_in[17];
  const float* W2  = (const float*)d_in[18];
  const float* as2 = (const float*)d_in[19];
  const float* ad2 = (const float*)d_in[20];
  const float* b2  = (const float*)d_in[21];
  float* out = (float*)d_out;

  int N = in_sizes[0] / 128;
  int E = in_sizes[1] / 2;
  int ET = E + N;
  int NBIN = (N + SNODES - 1) >> SBITS;   // 196 for N=100000 (<= NBIN_MAX)
  int M = NBIN * GLH;                     // Hmat/Bmat length (~50K)

  char* p = (char*)d_ws;
  auto alloc = [&](size_t bytes)->void* {
    void* r = (void*)p;
    p += (bytes + 255) & ~size_t(255);
    return r;
  };
  float* Wt2p  = (float*)alloc((size_t)128*64*4);
  int* deg     = (int*)alloc((size_t)N*4);
  int* offs    = (int*)alloc((size_t)(N+1)*4);
  int* partials= (int*)alloc(1024*4);
  int* Hmat    = (int*)alloc((size_t)NBIN_MAX*GLH*4);
  int* Bmat    = (int*)alloc((size_t)(NBIN_MAX*GLH+1)*4);
  int* csr     = (int*)alloc((size_t)ET*4);
  uint2* staged= (uint2*)alloc((size_t)ET*8);
  unsigned short* Pb = (unsigned short*)alloc((size_t)N*128*2);
  unsigned short* Gb = (unsigned short*)alloc((size_t)N*128*2);
  float* ALs = (float*)alloc((size_t)N*4*4);
  float* ALd = (float*)alloc((size_t)N*4*4);
  unsigned short* H2b = Pb;     // Pb free by the time layer-2 GEMM runs
  float* al2s = ALs;
  float* al2d = ALd;
  if ((size_t)(p - (char*)d_ws) > ws_size) return;  // workspace too small

  hipMemsetAsync(deg, 0, (size_t)N*4, stream);

  // weight prep (only W2 needs transpose+pad; W0/W1 feed MFMA as-is)
  k_padW2<<<(128*64+255)/256, 256, 0, stream>>>(W2, Wt2p);

  // ---- CSR build: deg->offs scan; local hists->Bmat scan; write; bucket scatter ----
  int nb1 = (N + 1023) / 1024;
  k_deg<<<(ET+255)/256, 256, 0, stream>>>(ei, E, N, deg);
  k_scan1<<<nb1, 256, 0, stream>>>(deg, offs+1, partials, N);
  k_scan2<<<1, 256, 0, stream>>>(partials, nb1);
  k_scan3<<<(N+255)/256, 256, 0, stream>>>(offs, partials, N);

  k_lhist<<<GLH, 256, 0, stream>>>(ei, E, N, Hmat, NBIN);
  int nb2 = (M + 1023) / 1024;
  k_scan1<<<nb2, 256, 0, stream>>>(Hmat, Bmat+1, partials, M);
  k_scan2<<<1, 256, 0, stream>>>(partials, nb2);
  k_scan3<<<(M+255)/256, 256, 0, stream>>>(Bmat, partials, M);
  k_write<<<GLH, 256, 0, stream>>>(ei, E, N, Bmat, staged, NBIN);
  k_bucket2<<<NBIN, 256, 0, stream>>>(staged, offs, csr, N);

  int gb = (N + 63) / 64;
  // ---- layer 0 ----
  k_gemm128m<false><<<gb, 256, 0, stream>>>(x, W0, as0, ad0, Pb, ALs, ALd, N);
  k_agg128b<<<(N+3)/4, 256, 0, stream>>>(Pb, ALs, ALd, offs, csr, b0, g0, be0, m0, v0, Gb, N);

  // ---- layer 1 ----
  k_gemm128m<true><<<gb, 256, 0, stream>>>(Gb, W1, as1, ad1, Pb, ALs, ALd, N);
  k_agg128b<<<(N+3)/4, 256, 0, stream>>>(Pb, ALs, ALd, offs, csr, b1, g1, be1, m1, v1, Gb, N);

  // ---- output layer ----
  k_gemm40n<<<gb, 256, 0, stream>>>(Gb, Wt2p, as2, ad2, H2b, al2s, al2d, N);
  k_agg40b<<<(N+3)/4, 256, 0, stream>>>(H2b, al2s, al2d, offs, csr, b2, out, N);
}

// Round 8
// 498.253 us; speedup vs baseline: 3.8231x; 1.1071x over previous
//
#include <hip/hip_runtime.h>
#include <math.h>

#define NEGS 0.2f
#define EPSBN 1e-5f
#define NBIN_MAX 256
#define SBITS 9
#define SNODES 512
#define GLH 256   // blocks for lhist/write

typedef __attribute__((ext_vector_type(8))) short short8v;   // 8 bf16 = 4 VGPR
typedef __attribute__((ext_vector_type(4))) float f32x4;     // MFMA acc

static __device__ __forceinline__ float lrelu(float x){ return x > 0.f ? x : NEGS*x; }
static __device__ __forceinline__ float bf_lo(unsigned u){ return __uint_as_float(u << 16); }
static __device__ __forceinline__ float bf_hi(unsigned u){ return __uint_as_float(u & 0xffff0000u); }
static __device__ __forceinline__ float bf1(unsigned short v){ return __uint_as_float(((unsigned)v) << 16); }
static __device__ __forceinline__ unsigned short f2bf(float f){
  unsigned u = __float_as_uint(f);
  unsigned r = (u + 0x7fff + ((u >> 16) & 1)) >> 16;   // RNE
  return (unsigned short)r;
}

// pad+transpose W2 [40][128] -> Wt2p [128][64] (cols >=40 zero)
__global__ void k_padW2(const float* __restrict__ W2, float* __restrict__ Wt2p){
  int i = blockIdx.x*256 + threadIdx.x;
  if (i >= 128*64) return;
  int k = i >> 6, c = i & 63;
  Wt2p[i] = (c < 40) ? W2[c*128 + k] : 0.f;
}

// generic 3-kernel exclusive scan (scan1 writes inclusive into incl[i] = out[i+1])
__global__ void k_scan1(const int* __restrict__ in, int* __restrict__ incl,
                        int* __restrict__ partials, int n){
  __shared__ int sd[256];
  int tid = threadIdx.x;
  int base = blockIdx.x*1024 + tid*4;
  int v[4]; int s = 0;
  #pragma unroll
  for (int j=0;j<4;++j){ int idx = base+j; v[j] = (idx<n)? in[idx] : 0; s += v[j]; }
  sd[tid] = s; __syncthreads();
  for (int off=1; off<256; off<<=1){
    int t = (tid>=off)? sd[tid-off] : 0;
    __syncthreads();
    sd[tid] += t;
    __syncthreads();
  }
  int run = sd[tid] - s;
  #pragma unroll
  for (int j=0;j<4;++j){ int idx = base+j; run += v[j]; if (idx<n) incl[idx] = run; }
  if (tid==255) partials[blockIdx.x] = sd[255];
}

__global__ void k_scan2(int* partials, int nb){
  __shared__ int sd[256];
  int tid = threadIdx.x;
  sd[tid] = (tid<nb)? partials[tid] : 0;
  __syncthreads();
  for (int off=1; off<256; off<<=1){
    int t = (tid>=off)? sd[tid-off] : 0;
    __syncthreads();
    sd[tid] += t;
    __syncthreads();
  }
  if (tid<nb) partials[tid] = sd[tid];
}

__global__ void k_scan3(int* __restrict__ offs, const int* __restrict__ partials, int n){
  int i = blockIdx.x*256 + threadIdx.x;
  if (i == 0) offs[0] = 0;
  if (i >= n) return;
  int b = i >> 10;
  if (b > 0) offs[i+1] += partials[b-1];
}

// ---------------- bucket-sort staging (contention-free) ----------------
// block-local LDS histogram over buckets -> Hmat[bin*GLH + block]
__global__ __launch_bounds__(256) void k_lhist(const int* __restrict__ ei, int E, int N,
                                               int* __restrict__ Hmat, int nbin){
  __shared__ int lh[NBIN_MAX];
  int tid = threadIdx.x;
  lh[tid] = 0;
  __syncthreads();
  int ET = E + N;
  int c0 = (int)(((long long)ET * blockIdx.x) / GLH);
  int c1 = (int)(((long long)ET * (blockIdx.x+1)) / GLH);
  for (int i = c0 + tid; i < c1; i += 256){
    int d = (i < E) ? ei[E + i] : (i - E);
    atomicAdd(&lh[d >> SBITS], 1);
  }
  __syncthreads();
  for (int b = tid; b < nbin; b += 256)
    Hmat[b*GLH + blockIdx.x] = lh[b];
}

// re-read edges, write (src,dst) into disjoint staged ranges (LDS cursors, no global atomics)
__global__ __launch_bounds__(256) void k_write(const int* __restrict__ ei, int E, int N,
                        const int* __restrict__ Bmat, uint2* __restrict__ staged, int nbin){
  __shared__ int cur[NBIN_MAX];
  int tid = threadIdx.x;
  for (int b = tid; b < nbin; b += 256)
    cur[b] = Bmat[b*GLH + blockIdx.x];
  __syncthreads();
  int ET = E + N;
  int c0 = (int)(((long long)ET * blockIdx.x) / GLH);
  int c1 = (int)(((long long)ET * (blockIdx.x+1)) / GLH);
  for (int i = c0 + tid; i < c1; i += 256){
    int s, d;
    if (i < E){ s = ei[i]; d = ei[E+i]; } else { s = i-E; d = i-E; }
    int pos = atomicAdd(&cur[d >> SBITS], 1);
    staged[pos] = make_uint2((unsigned)s, (unsigned)d);
  }
}

// one block per bucket: per-node degree + LDS scan -> offs, then scatter csr
// within the bucket's L2-resident window (LDS cursors). Replaces global k_deg+scan.
__global__ __launch_bounds__(256) void k_bucket3(const uint2* __restrict__ staged,
                         const int* __restrict__ Bmat,
                         int* __restrict__ offs, int* __restrict__ csr, int N, int ET){
  __shared__ int sdeg[SNODES];
  __shared__ int sexc[SNODES];
  int b = blockIdx.x, tid = threadIdx.x;
  int node0 = b << SBITS;
  int nn = min(SNODES, N - node0);
  int base = Bmat[b*GLH];
  int cntb = Bmat[(b+1)*GLH] - base;
  sdeg[2*tid] = 0; sdeg[2*tid+1] = 0;
  __syncthreads();
  for (int e = tid; e < cntb; e += 256){
    uint2 p = staged[base + e];
    atomicAdd(&sdeg[p.y - node0], 1);
  }
  __syncthreads();
  int v0 = sdeg[2*tid], v1 = sdeg[2*tid+1];
  int ps = v0 + v1;
  sexc[tid] = ps; __syncthreads();
  for (int off=1; off<256; off<<=1){
    int t = (tid>=off)? sexc[tid-off] : 0;
    __syncthreads();
    sexc[tid] += t;
    __syncthreads();
  }
  int excl_pair = sexc[tid] - ps;
  __syncthreads();
  sexc[2*tid]   = excl_pair;
  sexc[2*tid+1] = excl_pair + v0;
  if (2*tid   < nn) offs[node0 + 2*tid]   = base + excl_pair;
  if (2*tid+1 < nn) offs[node0 + 2*tid+1] = base + excl_pair + v0;
  sdeg[2*tid] = 0; sdeg[2*tid+1] = 0;
  __syncthreads();
  for (int e = tid; e < cntb; e += 256){
    uint2 p = staged[base + e];
    int ln = p.y - node0;
    int pos = base + sexc[ln] + atomicAdd(&sdeg[ln], 1);
    csr[pos] = (int)p.x;
  }
  if (b == gridDim.x - 1 && tid == 0) offs[N] = ET;
}

// ------- MFMA GEMM 128x128 (X f32 or bf16 in, bf16 out) + fused logits -------
template<bool BF16IN>
__global__ __launch_bounds__(256) void k_gemm128m(const void* __restrict__ Xin,
                          const float* __restrict__ W,
                          const float* __restrict__ as_, const float* __restrict__ ad_,
                          unsigned short* __restrict__ Yb,
                          float* __restrict__ ALs, float* __restrict__ ALd, int n){
  __shared__ short lds[24576];               // Wb 128x128 @0 (32KB), Xb 64x128 @16384 (16KB)
  unsigned* ldsW = (unsigned*)lds;           // 8192 dwords
  unsigned* ldsX = (unsigned*)(lds + 16384); // 4096 dwords
  int tid = threadIdx.x;
  int r0 = blockIdx.x*64;
  #pragma unroll
  for (int j=0;j<16;++j){
    int i = (256*j + tid)*4;
    int row = i >> 7;
    float4 v = *(const float4*)(W + i);
    int dw = i >> 1, lo = dw & 63, base = dw & ~63;
    int sw = base | (lo ^ ((row&7)<<2));
    uint2 p;
    p.x = (unsigned)f2bf(v.x) | ((unsigned)f2bf(v.y)<<16);
    p.y = (unsigned)f2bf(v.z) | ((unsigned)f2bf(v.w)<<16);
    *(uint2*)(&ldsW[sw]) = p;
  }
  if (!BF16IN){
    const float* X = (const float*)Xin;
    #pragma unroll
    for (int j=0;j<8;++j){
      int i = (256*j + tid)*4;
      int row = i >> 7;
      int grow = r0 + row;
      float4 v = (grow < n) ? *(const float4*)(X + (size_t)grow*128 + (i&127))
                            : make_float4(0.f,0.f,0.f,0.f);
      int dw = i >> 1, lo = dw & 63, base = dw & ~63;
      int sw = base | (lo ^ ((row&7)<<2));
      uint2 p;
      p.x = (unsigned)f2bf(v.x) | ((unsigned)f2bf(v.y)<<16);
      p.y = (unsigned)f2bf(v.z) | ((unsigned)f2bf(v.w)<<16);
      *(uint2*)(&ldsX[sw]) = p;
    }
  } else {
    const unsigned short* Xb = (const unsigned short*)Xin;
    #pragma unroll
    for (int j=0;j<4;++j){
      int dw4 = 1024*j + tid*4;
      int row = dw4 >> 6;
      int grow = r0 + row;
      uint4 v = (grow < n) ? *(const uint4*)(Xb + (size_t)grow*128 + (dw4&63)*2)
                           : make_uint4(0,0,0,0);
      int lo = dw4 & 63, base = dw4 & ~63;
      int sw = base | (lo ^ ((row&7)<<2));
      *(uint4*)(&ldsX[sw]) = v;
    }
  }
  __syncthreads();
  int l = tid & 63, w = tid >> 6;
  int lrow = l & 15, lk = l >> 4;
  int arow = w*16 + lrow;
  int abase = arow*64, ax = (arow&7)<<2;
  short8v a[4];
  #pragma unroll
  for (int ks=0;ks<4;++ks){
    int lo = ks*16 + lk*4;
    a[ks] = *(const short8v*)&ldsX[abase + (lo ^ ax)];
  }
  f32x4 acc[8];
  #pragma unroll
  for (int c=0;c<8;++c) acc[c] = (f32x4){0.f,0.f,0.f,0.f};
  #pragma unroll
  for (int c=0;c<8;++c){
    int brow = c*16 + lrow;
    int bbase2 = brow*64, bx = (brow&7)<<2;
    #pragma unroll
    for (int ks=0;ks<4;++ks){
      int lo = ks*16 + lk*4;
      short8v bfr = *(const short8v*)&ldsW[bbase2 + (lo ^ bx)];
      acc[c] = __builtin_amdgcn_mfma_f32_16x16x32_bf16(a[ks], bfr, acc[c], 0, 0, 0);
    }
  }
  __syncthreads();
  unsigned short* Ys = (unsigned short*)ldsX;
  #pragma unroll
  for (int c=0;c<8;++c){
    #pragma unroll
    for (int r=0;r<4;++r){
      int row = w*16 + lk*4 + r;
      Ys[row*128 + c*16 + lrow] = f2bf(acc[c][r]);
    }
  }
  __syncthreads();
  #pragma unroll
  for (int j=0;j<4;++j){
    int dw4 = 1024*j + tid*4;
    int row = dw4 >> 6;
    int grow = r0 + row;
    if (grow < n)
      *(uint4*)(Yb + (size_t)grow*128 + (dw4&63)*2) = *(const uint4*)&((unsigned*)ldsX)[dw4];
  }
  {
    int row = tid >> 2, h = tid & 3;
    int grow = r0 + row;
    if (grow < n){
      const unsigned short* yr = Ys + row*128 + h*32;
      float ps = 0.f, pd = 0.f;
      #pragma unroll
      for (int j=0;j<32;++j){
        float y = bf1(yr[j]);
        ps = fmaf(y, as_[h*32+j], ps);
        pd = fmaf(y, ad_[h*32+j], pd);
      }
      ALs[grow*4+h] = ps; ALd[grow*4+h] = pd;
    }
  }
}

// ------- fused GAT aggregation + bias + BN + ReLU -------
// one wave per node; 4 edges/step, 16 lanes/edge; softmax weights hoisted:
// per 16-edge chunk, lane (e<<2)|h computes w[e][h] once; MAC steps shfl it.
__global__ __launch_bounds__(256) void k_agg128b(const unsigned short* __restrict__ Pb,
                         const float* __restrict__ ALs, const float* __restrict__ ALd,
                         const int* __restrict__ offs, const int* __restrict__ csr,
                         const float* __restrict__ bias, const float* __restrict__ gam,
                         const float* __restrict__ bet, const float* __restrict__ mean,
                         const float* __restrict__ var, unsigned short* __restrict__ outb, int n){
  int node = blockIdx.x*4 + (threadIdx.x >> 6);
  int lane = threadIdx.x & 63;
  if (node >= n) return;
  int el = lane >> 4, fl = lane & 15, hd = fl >> 2;
  int beg = offs[node], end = offs[node+1];
  int deg = end - beg;
  float aldw = ALd[node*4 + (lane & 3)];       // head = lane&3 for weight phase
  int c = (lane < deg) ? csr[beg + lane] : 0;  // preload up to 64 edge indices
  float a0=0.f,a1=0.f,a2=0.f,a3=0.f,a4=0.f,a5=0.f,a6=0.f,a7=0.f;
  float wsum = 0.f;
  int nsteps = (deg + 3) >> 2;
  float wch = 0.f;
  int wbase = el*4 + hd;
  #pragma unroll 4
  for (int st = 0; st < nsteps; ++st){
    if ((st & 3) == 0){
      // weight phase: lane computes w for edge st*4+(lane>>2), head lane&3
      int we = st*4 + (lane >> 2);
      int ws = (we < 64) ? __shfl(c, we) : ((we < deg) ? csr[beg + we] : 0);
      float als = ALs[ws*4 + (lane & 3)];      // coalesced float4 per 4-lane group
      wch = (we < deg) ? __expf(lrelu(als + aldw)) : 0.f;
    }
    int idx = st*4 + el;
    float w = __shfl(wch, ((st & 3) << 4) + wbase);
    int si = (idx < 64) ? __shfl(c, idx) : ((idx < deg) ? csr[beg + idx] : 0);
    uint4 hv = *(const uint4*)(Pb + (size_t)si*128 + fl*8);
    wsum += w;
    a0 = fmaf(w, bf_lo(hv.x), a0);  a1 = fmaf(w, bf_hi(hv.x), a1);
    a2 = fmaf(w, bf_lo(hv.y), a2);  a3 = fmaf(w, bf_hi(hv.y), a3);
    a4 = fmaf(w, bf_lo(hv.z), a4);  a5 = fmaf(w, bf_hi(hv.z), a5);
    a6 = fmaf(w, bf_lo(hv.w), a6);  a7 = fmaf(w, bf_hi(hv.w), a7);
  }
  #pragma unroll
  for (int off=16; off<64; off<<=1){
    a0 += __shfl_xor(a0, off); a1 += __shfl_xor(a1, off);
    a2 += __shfl_xor(a2, off); a3 += __shfl_xor(a3, off);
    a4 += __shfl_xor(a4, off); a5 += __shfl_xor(a5, off);
    a6 += __shfl_xor(a6, off); a7 += __shfl_xor(a7, off);
    wsum += __shfl_xor(wsum, off);
  }
  if (el == 0){
    float inv = 1.f / wsum;
    int cc = fl*8;
    float4 bA = *(const float4*)(bias+cc), bB = *(const float4*)(bias+cc+4);
    float4 gA = *(const float4*)(gam+cc),  gB = *(const float4*)(gam+cc+4);
    float4 eA = *(const float4*)(bet+cc),  eB = *(const float4*)(bet+cc+4);
    float4 uA = *(const float4*)(mean+cc), uB = *(const float4*)(mean+cc+4);
    float4 vA = *(const float4*)(var+cc),  vB = *(const float4*)(var+cc+4);
    float o0 = (a0*inv + bA.x - uA.x) * rsqrtf(vA.x + EPSBN) * gA.x + eA.x;
    float o1 = (a1*inv + bA.y - uA.y) * rsqrtf(vA.y + EPSBN) * gA.y + eA.y;
    float o2 = (a2*inv + bA.z - uA.z) * rsqrtf(vA.z + EPSBN) * gA.z + eA.z;
    float o3 = (a3*inv + bA.w - uA.w) * rsqrtf(vA.w + EPSBN) * gA.w + eA.w;
    float o4 = (a4*inv + bB.x - uB.x) * rsqrtf(vB.x + EPSBN) * gB.x + eB.x;
    float o5 = (a5*inv + bB.y - uB.y) * rsqrtf(vB.y + EPSBN) * gB.y + eB.y;
    float o6 = (a6*inv + bB.z - uB.z) * rsqrtf(vB.z + EPSBN) * gB.z + eB.z;
    float o7 = (a7*inv + bB.w - uB.w) * rsqrtf(vB.w + EPSBN) * gB.w + eB.w;
    uint4 q;
    q.x = (unsigned)f2bf(fmaxf(o0,0.f)) | ((unsigned)f2bf(fmaxf(o1,0.f))<<16);
    q.y = (unsigned)f2bf(fmaxf(o2,0.f)) | ((unsigned)f2bf(fmaxf(o3,0.f))<<16);
    q.z = (unsigned)f2bf(fmaxf(o4,0.f)) | ((unsigned)f2bf(fmaxf(o5,0.f))<<16);
    q.w = (unsigned)f2bf(fmaxf(o6,0.f)) | ((unsigned)f2bf(fmaxf(o7,0.f))<<16);
    *(uint4*)(outb + (size_t)node*128 + cc) = q;
  }
}

// ------- output layer GEMM (bf16 in, 128->40 padded 64, bf16 H2 out) + fused logits -------
__global__ __launch_bounds__(256) void k_gemm40n(const unsigned short* __restrict__ Gb,
                                                 const float* __restrict__ Wt2p,
                                                 const float* __restrict__ as2,
                                                 const float* __restrict__ ad2,
                                                 unsigned short* __restrict__ H2b,
                                                 float* __restrict__ al2s,
                                                 float* __restrict__ al2d, int n){
  __shared__ float xt[128*68];   // xt[k*68 + r], r in [0,64)
  int tid = threadIdx.x;
  int r0 = blockIdx.x * 64;
  {
    int r  = tid & 63;
    int c0 = (tid >> 6) * 32;
    int row = r0 + r;
    #pragma unroll
    for (int j=0;j<4;++j){
      uint4 v = (row < n) ? *(const uint4*)(Gb + (size_t)row*128 + c0 + j*8)
                          : make_uint4(0,0,0,0);
      int k = c0 + j*8;
      xt[(k+0)*68 + r] = bf_lo(v.x);  xt[(k+1)*68 + r] = bf_hi(v.x);
      xt[(k+2)*68 + r] = bf_lo(v.y);  xt[(k+3)*68 + r] = bf_hi(v.y);
      xt[(k+4)*68 + r] = bf_lo(v.z);  xt[(k+5)*68 + r] = bf_hi(v.z);
      xt[(k+6)*68 + r] = bf_lo(v.w);  xt[(k+7)*68 + r] = bf_hi(v.w);
    }
  }
  __syncthreads();
  int tc = tid & 15, tr = tid >> 4;
  float acc[4][4] = {};
  #pragma unroll 4
  for (int k=0;k<128;++k){
    float4 wv = *(const float4*)(Wt2p + k*64 + tc*4);
    float4 xv = *(const float4*)(&xt[k*68 + tr*4]);
    float xv4[4] = {xv.x, xv.y, xv.z, xv.w};
    float wv4[4] = {wv.x, wv.y, wv.z, wv.w};
    #pragma unroll
    for (int u=0;u<4;++u)
      #pragma unroll
      for (int v=0;v<4;++v)
        acc[u][v] = fmaf(xv4[u], wv4[v], acc[u][v]);
  }
  float4 a4 = make_float4(0.f,0.f,0.f,0.f), d4 = a4;
  if (tc < 10){
    a4 = *(const float4*)(as2 + tc*4);
    d4 = *(const float4*)(ad2 + tc*4);
  }
  #pragma unroll
  for (int u=0;u<4;++u){
    int row = r0 + tr*4 + u;
    float ps = acc[u][0]*a4.x + acc[u][1]*a4.y + acc[u][2]*a4.z + acc[u][3]*a4.w;
    float pd = acc[u][0]*d4.x + acc[u][1]*d4.y + acc[u][2]*d4.z + acc[u][3]*d4.w;
    #pragma unroll
    for (int m=1; m<16; m<<=1){ ps += __shfl_xor(ps,m); pd += __shfl_xor(pd,m); }
    if (row < n){
      if (tc < 10){
        ushort4 o;
        o.x = f2bf(acc[u][0]); o.y = f2bf(acc[u][1]);
        o.z = f2bf(acc[u][2]); o.w = f2bf(acc[u][3]);
        *(ushort4*)(H2b + (size_t)row*40 + tc*4) = o;
      }
      if (tc == 0){ al2s[row] = ps; al2d[row] = pd; }
    }
  }
}

// ------- output aggregation + bias + log_softmax (8 edges/step, hoisted weights) -------
__global__ __launch_bounds__(256) void k_agg40b(const unsigned short* __restrict__ H2b,
                        const float* __restrict__ ALs, const float* __restrict__ ALd,
                        const int* __restrict__ offs, const int* __restrict__ csr,
                        const float* __restrict__ b2, float* __restrict__ out, int n){
  int node = blockIdx.x*4 + (threadIdx.x >> 6);
  int lane = threadIdx.x & 63;
  if (node >= n) return;
  int el = lane >> 3, fl = lane & 7;
  bool act = fl < 5;
  int beg = offs[node], end = offs[node+1];
  int deg = end - beg;
  float ald = ALd[node];
  int c = (lane < deg) ? csr[beg + lane] : 0;
  float a0=0.f,a1=0.f,a2=0.f,a3=0.f,a4=0.f,a5=0.f,a6=0.f,a7=0.f;
  float wsum = 0.f;
  int nsteps = (deg + 7) >> 3;
  float wch = 0.f;
  #pragma unroll 4
  for (int st = 0; st < nsteps; ++st){
    if ((st & 7) == 0){
      // weight phase: lane computes w for edge st*8+lane (chunk of 64)
      int we = st*8 + lane;
      int ws = (we < 64) ? __shfl(c, we) : ((we < deg) ? csr[beg + we] : 0);
      float als = ALs[ws];
      wch = (we < deg) ? __expf(lrelu(als + ald)) : 0.f;
    }
    int idx = st*8 + el;
    float w = __shfl(wch, ((st & 7) << 3) + el);
    int si = (idx < 64) ? __shfl(c, idx) : ((idx < deg) ? csr[beg + idx] : 0);
    wsum += w;
    if (act){
      uint4 hv = *(const uint4*)(H2b + (size_t)si*40 + fl*8);
      a0 = fmaf(w, bf_lo(hv.x), a0);  a1 = fmaf(w, bf_hi(hv.x), a1);
      a2 = fmaf(w, bf_lo(hv.y), a2);  a3 = fmaf(w, bf_hi(hv.y), a3);
      a4 = fmaf(w, bf_lo(hv.z), a4);  a5 = fmaf(w, bf_hi(hv.z), a5);
      a6 = fmaf(w, bf_lo(hv.w), a6);  a7 = fmaf(w, bf_hi(hv.w), a7);
    }
  }
  #pragma unroll
  for (int off=8; off<64; off<<=1){
    a0 += __shfl_xor(a0, off); a1 += __shfl_xor(a1, off);
    a2 += __shfl_xor(a2, off); a3 += __shfl_xor(a3, off);
    a4 += __shfl_xor(a4, off); a5 += __shfl_xor(a5, off);
    a6 += __shfl_xor(a6, off); a7 += __shfl_xor(a7, off);
    wsum += __shfl_xor(wsum, off);
  }
  if (el == 0){
    float inv = 1.f / wsum;
    float y0=0.f,y1=0.f,y2=0.f,y3=0.f,y4=0.f,y5=0.f,y6=0.f,y7=0.f;
    if (act){
      int cc = fl*8;
      float4 bA = *(const float4*)(b2 + cc), bB = *(const float4*)(b2 + cc + 4);
      y0 = a0*inv + bA.x; y1 = a1*inv + bA.y; y2 = a2*inv + bA.z; y3 = a3*inv + bA.w;
      y4 = a4*inv + bB.x; y5 = a5*inv + bB.y; y6 = a6*inv + bB.z; y7 = a7*inv + bB.w;
    }
    float lm = act ? fmaxf(fmaxf(fmaxf(y0,y1),fmaxf(y2,y3)),
                           fmaxf(fmaxf(y4,y5),fmaxf(y6,y7))) : -1e30f;
    lm = fmaxf(lm, __shfl_xor(lm,1));
    lm = fmaxf(lm, __shfl_xor(lm,2));
    lm = fmaxf(lm, __shfl_xor(lm,4));
    float ls = act ? (__expf(y0-lm)+__expf(y1-lm)+__expf(y2-lm)+__expf(y3-lm)
                     +__expf(y4-lm)+__expf(y5-lm)+__expf(y6-lm)+__expf(y7-lm)) : 0.f;
    ls += __shfl_xor(ls,1);
    ls += __shfl_xor(ls,2);
    ls += __shfl_xor(ls,4);
    float lg = lm + __logf(ls);
    if (act){
      float4* dst = (float4*)(out + (size_t)node*40 + fl*8);
      dst[0] = make_float4(y0-lg, y1-lg, y2-lg, y3-lg);
      dst[1] = make_float4(y4-lg, y5-lg, y6-lg, y7-lg);
    }
  }
}

extern "C" void kernel_launch(void* const* d_in, const int* in_sizes, int n_in,
                              void* d_out, int out_size, void* d_ws, size_t ws_size,
                              hipStream_t stream) {
  const float* x   = (const float*)d_in[0];
  const int*   ei  = (const int*)d_in[1];
  const float* W0  = (const float*)d_in[2];
  const float* as0 = (const float*)d_in[3];
  const float* ad0 = (const float*)d_in[4];
  const float* b0  = (const float*)d_in[5];
  const float* g0  = (const float*)d_in[6];
  const float* be0 = (const float*)d_in[7];
  const float* m0  = (const float*)d_in[8];
  const float* v0  = (const float*)d_in[9];
  const float* W1  = (const float*)d_in[10];
  const float* as1 = (const float*)d_in[11];
  const float* ad1 = (const float*)d_in[12];
  const float* b1  = (const float*)d_in[13];
  const float* g1  = (const float*)d_in[14];
  const float* be1 = (const float*)d_in[15];
  const float* m1  = (const float*)d_in[16];
  const float* v1  = (const float*)d_in[17];
  const float* W2  = (const float*)d_in[18];
  const float* as2 = (const float*)d_in[19];
  const float* ad2 = (const float*)d_in[20];
  const float* b2  = (const float*)d_in[21];
  float* out = (float*)d_out;

  int N = in_sizes[0] / 128;
  int E = in_sizes[1] / 2;
  int ET = E + N;
  int NBIN = (N + SNODES - 1) >> SBITS;   // 196 for N=100000 (<= NBIN_MAX)
  int M = NBIN * GLH;                     // Hmat/Bmat length (~50K)

  char* p = (char*)d_ws;
  auto alloc = [&](size_t bytes)->void* {
    void* r = (void*)p;
    p += (bytes + 255) & ~size_t(255);
    return r;
  };
  float* Wt2p  = (float*)alloc((size_t)128*64*4);
  int* offs    = (int*)alloc((size_t)(N+1)*4);
  int* partials= (int*)alloc(1024*4);
  int* Hmat    = (int*)alloc((size_t)NBIN_MAX*GLH*4);
  int* Bmat    = (int*)alloc((size_t)(NBIN_MAX*GLH+1)*4);
  int* csr     = (int*)alloc((size_t)ET*4);
  uint2* staged= (uint2*)alloc((size_t)ET*8);
  unsigned short* Pb = (unsigned short*)alloc((size_t)N*128*2);
  unsigned short* Gb = (unsigned short*)alloc((size_t)N*128*2);
  float* ALs = (float*)alloc((size_t)N*4*4);
  float* ALd = (float*)alloc((size_t)N*4*4);
  unsigned short* H2b = Pb;     // Pb free by the time layer-2 GEMM runs
  float* al2s = ALs;
  float* al2d = ALd;
  if ((size_t)(p - (char*)d_ws) > ws_size) return;  // workspace too small

  // weight prep (only W2 needs transpose+pad; W0/W1 feed MFMA as-is)
  k_padW2<<<(128*64+255)/256, 256, 0, stream>>>(W2, Wt2p);

  // ---- CSR build: local hists -> Bmat scan -> bucketed write -> per-bucket offs+csr ----
  k_lhist<<<GLH, 256, 0, stream>>>(ei, E, N, Hmat, NBIN);
  int nb2 = (M + 1023) / 1024;
  k_scan1<<<nb2, 256, 0, stream>>>(Hmat, Bmat+1, partials, M);
  k_scan2<<<1, 256, 0, stream>>>(partials, nb2);
  k_scan3<<<(M+255)/256, 256, 0, stream>>>(Bmat, partials, M);
  k_write<<<GLH, 256, 0, stream>>>(ei, E, N, Bmat, staged, NBIN);
  k_bucket3<<<NBIN, 256, 0, stream>>>(staged, Bmat, offs, csr, N, ET);

  int gb = (N + 63) / 64;
  // ---- layer 0 ----
  k_gemm128m<false><<<gb, 256, 0, stream>>>(x, W0, as0, ad0, Pb, ALs, ALd, N);
  k_agg128b<<<(N+3)/4, 256, 0, stream>>>(Pb, ALs, ALd, offs, csr, b0, g0, be0, m0, v0, Gb, N);

  // ---- layer 1 ----
  k_gemm128m<true><<<gb, 256, 0, stream>>>(Gb, W1, as1, ad1, Pb, ALs, ALd, N);
  k_agg128b<<<(N+3)/4, 256, 0, stream>>>(Pb, ALs, ALd, offs, csr, b1, g1, be1, m1, v1, Gb, N);

  // ---- output layer ----
  k_gemm40n<<<gb, 256, 0, stream>>>(Gb, Wt2p, as2, ad2, H2b, al2s, al2d, N);
  k_agg40b<<<(N+3)/4, 256, 0, stream>>>(H2b, al2s, al2d, offs, csr, b2, out, N);
}

// Round 9
// 481.552 us; speedup vs baseline: 3.9557x; 1.0347x over previous
//
#include <hip/hip_runtime.h>
#include <math.h>

#define NEGS 0.2f
#define EPSBN 1e-5f
#define NBIN_MAX 256
#define SBITS 9
#define SNODES 512
#define GLH 256   // blocks for lhist/write

typedef __attribute__((ext_vector_type(8))) short short8v;   // 8 bf16 = 4 VGPR
typedef __attribute__((ext_vector_type(4))) float f32x4;     // MFMA acc

static __device__ __forceinline__ float lrelu(float x){ return x > 0.f ? x : NEGS*x; }
static __device__ __forceinline__ float bf_lo(unsigned u){ return __uint_as_float(u << 16); }
static __device__ __forceinline__ float bf_hi(unsigned u){ return __uint_as_float(u & 0xffff0000u); }
static __device__ __forceinline__ float bf1(unsigned short v){ return __uint_as_float(((unsigned)v) << 16); }
static __device__ __forceinline__ unsigned short f2bf(float f){
  unsigned u = __float_as_uint(f);
  unsigned r = (u + 0x7fff + ((u >> 16) & 1)) >> 16;   // RNE
  return (unsigned short)r;
}

// ---- weight prep: W0,W1 -> bf16 row-major; W2 -> padded transpose [128][64] ----
__global__ void k_prep(const float* __restrict__ W0, const float* __restrict__ W1,
                       const float* __restrict__ W2, unsigned short* __restrict__ Wb0,
                       unsigned short* __restrict__ Wb1, float* __restrict__ Wt2p){
  int i = blockIdx.x*256 + threadIdx.x;
  if (i < 16384){ Wb0[i] = f2bf(W0[i]); return; }
  if (i < 32768){ Wb1[i-16384] = f2bf(W1[i-16384]); return; }
  if (i < 40960){
    int j = i - 32768;
    int k = j >> 6, c = j & 63;
    Wt2p[j] = (c < 40) ? W2[c*128 + k] : 0.f;
  }
}

// generic 3-kernel exclusive scan (scan1 writes inclusive into incl[i] = out[i+1])
__global__ void k_scan1(const int* __restrict__ in, int* __restrict__ incl,
                        int* __restrict__ partials, int n){
  __shared__ int sd[256];
  int tid = threadIdx.x;
  int base = blockIdx.x*1024 + tid*4;
  int v[4]; int s = 0;
  #pragma unroll
  for (int j=0;j<4;++j){ int idx = base+j; v[j] = (idx<n)? in[idx] : 0; s += v[j]; }
  sd[tid] = s; __syncthreads();
  for (int off=1; off<256; off<<=1){
    int t = (tid>=off)? sd[tid-off] : 0;
    __syncthreads();
    sd[tid] += t;
    __syncthreads();
  }
  int run = sd[tid] - s;
  #pragma unroll
  for (int j=0;j<4;++j){ int idx = base+j; run += v[j]; if (idx<n) incl[idx] = run; }
  if (tid==255) partials[blockIdx.x] = sd[255];
}

__global__ void k_scan2(int* partials, int nb){
  __shared__ int sd[256];
  int tid = threadIdx.x;
  sd[tid] = (tid<nb)? partials[tid] : 0;
  __syncthreads();
  for (int off=1; off<256; off<<=1){
    int t = (tid>=off)? sd[tid-off] : 0;
    __syncthreads();
    sd[tid] += t;
    __syncthreads();
  }
  if (tid<nb) partials[tid] = sd[tid];
}

__global__ void k_scan3(int* __restrict__ offs, const int* __restrict__ partials, int n){
  int i = blockIdx.x*256 + threadIdx.x;
  if (i == 0) offs[0] = 0;
  if (i >= n) return;
  int b = i >> 10;
  if (b > 0) offs[i+1] += partials[b-1];
}

// ---------------- bucket-sort staging (contention-free) ----------------
__global__ __launch_bounds__(256) void k_lhist(const int* __restrict__ ei, int E, int N,
                                               int* __restrict__ Hmat, int nbin){
  __shared__ int lh[NBIN_MAX];
  int tid = threadIdx.x;
  lh[tid] = 0;
  __syncthreads();
  int ET = E + N;
  int c0 = (int)(((long long)ET * blockIdx.x) / GLH);
  int c1 = (int)(((long long)ET * (blockIdx.x+1)) / GLH);
  for (int i = c0 + tid; i < c1; i += 256){
    int d = (i < E) ? ei[E + i] : (i - E);
    atomicAdd(&lh[d >> SBITS], 1);
  }
  __syncthreads();
  for (int b = tid; b < nbin; b += 256)
    Hmat[b*GLH + blockIdx.x] = lh[b];
}

// write packed (dlocal<<23)|src into disjoint staged ranges (LDS cursors)
__global__ __launch_bounds__(256) void k_write(const int* __restrict__ ei, int E, int N,
                        const int* __restrict__ Bmat, unsigned* __restrict__ staged, int nbin){
  __shared__ int cur[NBIN_MAX];
  int tid = threadIdx.x;
  for (int b = tid; b < nbin; b += 256)
    cur[b] = Bmat[b*GLH + blockIdx.x];
  __syncthreads();
  int ET = E + N;
  int c0 = (int)(((long long)ET * blockIdx.x) / GLH);
  int c1 = (int)(((long long)ET * (blockIdx.x+1)) / GLH);
  for (int i = c0 + tid; i < c1; i += 256){
    int s, d;
    if (i < E){ s = ei[i]; d = ei[E+i]; } else { s = i-E; d = i-E; }
    int pos = atomicAdd(&cur[d >> SBITS], 1);
    staged[pos] = (unsigned)s | ((unsigned)(d & (SNODES-1)) << 23);
  }
}

// one block per bucket: per-node degree + LDS scan -> offs, then csr scatter
__global__ __launch_bounds__(256) void k_bucket3(const unsigned* __restrict__ staged,
                         const int* __restrict__ Bmat,
                         int* __restrict__ offs, int* __restrict__ csr, int N, int ET){
  __shared__ int sdeg[SNODES];
  __shared__ int sexc[SNODES];
  int b = blockIdx.x, tid = threadIdx.x;
  int node0 = b << SBITS;
  int nn = min(SNODES, N - node0);
  int base = Bmat[b*GLH];
  int cntb = Bmat[(b+1)*GLH] - base;
  sdeg[2*tid] = 0; sdeg[2*tid+1] = 0;
  __syncthreads();
  for (int e = tid; e < cntb; e += 256){
    unsigned p = staged[base + e];
    atomicAdd(&sdeg[p >> 23], 1);
  }
  __syncthreads();
  int v0 = sdeg[2*tid], v1 = sdeg[2*tid+1];
  int ps = v0 + v1;
  sexc[tid] = ps; __syncthreads();
  for (int off=1; off<256; off<<=1){
    int t = (tid>=off)? sexc[tid-off] : 0;
    __syncthreads();
    sexc[tid] += t;
    __syncthreads();
  }
  int excl_pair = sexc[tid] - ps;
  __syncthreads();
  sexc[2*tid]   = excl_pair;
  sexc[2*tid+1] = excl_pair + v0;
  if (2*tid   < nn) offs[node0 + 2*tid]   = base + excl_pair;
  if (2*tid+1 < nn) offs[node0 + 2*tid+1] = base + excl_pair + v0;
  sdeg[2*tid] = 0; sdeg[2*tid+1] = 0;
  __syncthreads();
  for (int e = tid; e < cntb; e += 256){
    unsigned p = staged[base + e];
    int ln = p >> 23;
    int pos = base + sexc[ln] + atomicAdd(&sdeg[ln], 1);
    csr[pos] = (int)(p & 0x7FFFFFu);
  }
  if (b == gridDim.x - 1 && tid == 0) offs[N] = ET;
}

// ------- MFMA GEMM 128x128 (X f32 or bf16 in, W pre-converted bf16, bf16 out) + fused logits -------
template<bool BF16IN>
__global__ __launch_bounds__(256) void k_gemm128m(const void* __restrict__ Xin,
                          const unsigned short* __restrict__ Wb,
                          const float* __restrict__ as_, const float* __restrict__ ad_,
                          unsigned short* __restrict__ Yb,
                          float* __restrict__ ALs, float* __restrict__ ALd, int n){
  __shared__ short lds[24576];               // Wb 128x128 @0 (32KB), Xb 64x128 @16384 (16KB)
  unsigned* ldsW = (unsigned*)lds;           // 8192 dwords
  unsigned* ldsX = (unsigned*)(lds + 16384); // 4096 dwords
  int tid = threadIdx.x;
  int r0 = blockIdx.x*64;
  // stage W (bf16, swizzled): 8 x uint4 per thread
  #pragma unroll
  for (int j=0;j<8;++j){
    int dw4 = 1024*j + tid*4;
    int row = dw4 >> 6;
    uint4 v = *(const uint4*)(Wb + (size_t)dw4*2);
    int lo = dw4 & 63, base = dw4 & ~63;
    *(uint4*)(&ldsW[base | (lo ^ ((row&7)<<2))]) = v;
  }
  if (!BF16IN){
    const float* X = (const float*)Xin;
    #pragma unroll
    for (int j=0;j<8;++j){
      int i = (256*j + tid)*4;
      int row = i >> 7;
      int grow = r0 + row;
      float4 v = (grow < n) ? *(const float4*)(X + (size_t)grow*128 + (i&127))
                            : make_float4(0.f,0.f,0.f,0.f);
      int dw = i >> 1, lo = dw & 63, base = dw & ~63;
      int sw = base | (lo ^ ((row&7)<<2));
      uint2 p;
      p.x = (unsigned)f2bf(v.x) | ((unsigned)f2bf(v.y)<<16);
      p.y = (unsigned)f2bf(v.z) | ((unsigned)f2bf(v.w)<<16);
      *(uint2*)(&ldsX[sw]) = p;
    }
  } else {
    const unsigned short* Xb = (const unsigned short*)Xin;
    #pragma unroll
    for (int j=0;j<4;++j){
      int dw4 = 1024*j + tid*4;
      int row = dw4 >> 6;
      int grow = r0 + row;
      uint4 v = (grow < n) ? *(const uint4*)(Xb + (size_t)grow*128 + (dw4&63)*2)
                           : make_uint4(0,0,0,0);
      int lo = dw4 & 63, base = dw4 & ~63;
      int sw = base | (lo ^ ((row&7)<<2));
      *(uint4*)(&ldsX[sw]) = v;
    }
  }
  __syncthreads();
  int l = tid & 63, w = tid >> 6;
  int lrow = l & 15, lk = l >> 4;
  int arow = w*16 + lrow;
  int abase = arow*64, ax = (arow&7)<<2;
  short8v a[4];
  #pragma unroll
  for (int ks=0;ks<4;++ks){
    int lo = ks*16 + lk*4;
    a[ks] = *(const short8v*)&ldsX[abase + (lo ^ ax)];
  }
  f32x4 acc[8];
  #pragma unroll
  for (int c=0;c<8;++c) acc[c] = (f32x4){0.f,0.f,0.f,0.f};
  #pragma unroll
  for (int c=0;c<8;++c){
    int brow = c*16 + lrow;
    int bbase2 = brow*64, bx = (brow&7)<<2;
    #pragma unroll
    for (int ks=0;ks<4;++ks){
      int lo = ks*16 + lk*4;
      short8v bfr = *(const short8v*)&ldsW[bbase2 + (lo ^ bx)];
      acc[c] = __builtin_amdgcn_mfma_f32_16x16x32_bf16(a[ks], bfr, acc[c], 0, 0, 0);
    }
  }
  __syncthreads();
  unsigned short* Ys = (unsigned short*)ldsX;
  #pragma unroll
  for (int c=0;c<8;++c){
    #pragma unroll
    for (int r=0;r<4;++r){
      int row = w*16 + lk*4 + r;
      Ys[row*128 + c*16 + lrow] = f2bf(acc[c][r]);
    }
  }
  __syncthreads();
  #pragma unroll
  for (int j=0;j<4;++j){
    int dw4 = 1024*j + tid*4;
    int row = dw4 >> 6;
    int grow = r0 + row;
    if (grow < n)
      *(uint4*)(Yb + (size_t)grow*128 + (dw4&63)*2) = *(const uint4*)&((unsigned*)ldsX)[dw4];
  }
  {
    int row = tid >> 2, h = tid & 3;
    int grow = r0 + row;
    if (grow < n){
      const unsigned short* yr = Ys + row*128 + h*32;
      float ps = 0.f, pd = 0.f;
      #pragma unroll
      for (int j=0;j<32;++j){
        float y = bf1(yr[j]);
        ps = fmaf(y, as_[h*32+j], ps);
        pd = fmaf(y, ad_[h*32+j], pd);
      }
      ALs[grow*4+h] = ps; ALd[grow*4+h] = pd;
    }
  }
}

// ------- fused GAT aggregation + bias + BN + ReLU -------
// one wave per node; 4 edges/step, 16 lanes/edge. Weights for the preloaded 64
// edges computed UPFRONT (4 chunks, 4 parallel ALs gathers + 4 exps); MAC loop
// is pure shfl+gather+fma with 1-step row prefetch. Inline-exp tail for deg>64.
__global__ __launch_bounds__(256) void k_agg128b(const unsigned short* __restrict__ Pb,
                         const float* __restrict__ ALs, const float* __restrict__ ALd,
                         const int* __restrict__ offs, const int* __restrict__ csr,
                         const float* __restrict__ bias, const float* __restrict__ gam,
                         const float* __restrict__ bet, const float* __restrict__ mean,
                         const float* __restrict__ var, unsigned short* __restrict__ outb, int n){
  int node = blockIdx.x*4 + (threadIdx.x >> 6);
  int lane = threadIdx.x & 63;
  if (node >= n) return;
  int el = lane >> 4, fl = lane & 15, hd = fl >> 2;
  int beg = offs[node], end = offs[node+1];
  int deg = end - beg;
  float aldw = ALd[node*4 + (lane & 3)];
  int c = (lane < deg) ? csr[beg + lane] : 0;   // preload up to 64 edge indices
  // upfront weights: lane handles edge (chunk*16 + lane>>2), head lane&3
  float w0, w1, w2, w3;
  {
    int e0 = lane >> 2, h0 = lane & 3;
    int s0 = __shfl(c, e0), s1 = __shfl(c, 16+e0);
    int s2 = __shfl(c, 32+e0), s3 = __shfl(c, 48+e0);
    float al0 = ALs[s0*4+h0], al1 = ALs[s1*4+h0];
    float al2 = ALs[s2*4+h0], al3 = ALs[s3*4+h0];
    w0 = (e0      < deg) ? __expf(lrelu(al0 + aldw)) : 0.f;
    w1 = (16 + e0 < deg) ? __expf(lrelu(al1 + aldw)) : 0.f;
    w2 = (32 + e0 < deg) ? __expf(lrelu(al2 + aldw)) : 0.f;
    w3 = (48 + e0 < deg) ? __expf(lrelu(al3 + aldw)) : 0.f;
  }
  float a0=0.f,a1=0.f,a2=0.f,a3=0.f,a4=0.f,a5=0.f,a6=0.f,a7=0.f;
  float wsum = 0.f;
  int nsteps = (deg + 3) >> 2;
  int ns64 = min(nsteps, 16);
  uint4 hv;
  {
    int si = __shfl(c, el);
    hv = *(const uint4*)(Pb + (size_t)si*128 + fl*8);
  }
  for (int st = 0; st < ns64; ++st){
    int q = st >> 2, r = st & 3;
    float wc = (q==0) ? w0 : (q==1) ? w1 : (q==2) ? w2 : w3;
    float w = __shfl(wc, (r*4 + el)*4 + hd);
    uint4 hvN = make_uint4(0,0,0,0);
    if (st + 1 < ns64){
      int siN = __shfl(c, (st+1)*4 + el);
      hvN = *(const uint4*)(Pb + (size_t)siN*128 + fl*8);
    }
    wsum += w;
    a0 = fmaf(w, bf_lo(hv.x), a0);  a1 = fmaf(w, bf_hi(hv.x), a1);
    a2 = fmaf(w, bf_lo(hv.y), a2);  a3 = fmaf(w, bf_hi(hv.y), a3);
    a4 = fmaf(w, bf_lo(hv.z), a4);  a5 = fmaf(w, bf_hi(hv.z), a5);
    a6 = fmaf(w, bf_lo(hv.w), a6);  a7 = fmaf(w, bf_hi(hv.w), a7);
    hv = hvN;
  }
  // tail for deg > 64 (rare): inline exp per edge-group
  if (deg > 64){
    float aldh = __shfl(aldw, hd);
    for (int idx = 64 + el; idx < deg; idx += 4){
      int si = csr[beg + idx];
      float w = __expf(lrelu(ALs[si*4 + hd] + aldh));
      uint4 h4 = *(const uint4*)(Pb + (size_t)si*128 + fl*8);
      wsum += w;
      a0 = fmaf(w, bf_lo(h4.x), a0);  a1 = fmaf(w, bf_hi(h4.x), a1);
      a2 = fmaf(w, bf_lo(h4.y), a2);  a3 = fmaf(w, bf_hi(h4.y), a3);
      a4 = fmaf(w, bf_lo(h4.z), a4);  a5 = fmaf(w, bf_hi(h4.z), a5);
      a6 = fmaf(w, bf_lo(h4.w), a6);  a7 = fmaf(w, bf_hi(h4.w), a7);
    }
  }
  #pragma unroll
  for (int off=16; off<64; off<<=1){
    a0 += __shfl_xor(a0, off); a1 += __shfl_xor(a1, off);
    a2 += __shfl_xor(a2, off); a3 += __shfl_xor(a3, off);
    a4 += __shfl_xor(a4, off); a5 += __shfl_xor(a5, off);
    a6 += __shfl_xor(a6, off); a7 += __shfl_xor(a7, off);
    wsum += __shfl_xor(wsum, off);
  }
  if (el == 0){
    float inv = 1.f / wsum;
    int cc = fl*8;
    float4 bA = *(const float4*)(bias+cc), bB = *(const float4*)(bias+cc+4);
    float4 gA = *(const float4*)(gam+cc),  gB = *(const float4*)(gam+cc+4);
    float4 eA = *(const float4*)(bet+cc),  eB = *(const float4*)(bet+cc+4);
    float4 uA = *(const float4*)(mean+cc), uB = *(const float4*)(mean+cc+4);
    float4 vA = *(const float4*)(var+cc),  vB = *(const float4*)(var+cc+4);
    float o0 = (a0*inv + bA.x - uA.x) * rsqrtf(vA.x + EPSBN) * gA.x + eA.x;
    float o1 = (a1*inv + bA.y - uA.y) * rsqrtf(vA.y + EPSBN) * gA.y + eA.y;
    float o2 = (a2*inv + bA.z - uA.z) * rsqrtf(vA.z + EPSBN) * gA.z + eA.z;
    float o3 = (a3*inv + bA.w - uA.w) * rsqrtf(vA.w + EPSBN) * gA.w + eA.w;
    float o4 = (a4*inv + bB.x - uB.x) * rsqrtf(vB.x + EPSBN) * gB.x + eB.x;
    float o5 = (a5*inv + bB.y - uB.y) * rsqrtf(vB.y + EPSBN) * gB.y + eB.y;
    float o6 = (a6*inv + bB.z - uB.z) * rsqrtf(vB.z + EPSBN) * gB.z + eB.z;
    float o7 = (a7*inv + bB.w - uB.w) * rsqrtf(vB.w + EPSBN) * gB.w + eB.w;
    uint4 q;
    q.x = (unsigned)f2bf(fmaxf(o0,0.f)) | ((unsigned)f2bf(fmaxf(o1,0.f))<<16);
    q.y = (unsigned)f2bf(fmaxf(o2,0.f)) | ((unsigned)f2bf(fmaxf(o3,0.f))<<16);
    q.z = (unsigned)f2bf(fmaxf(o4,0.f)) | ((unsigned)f2bf(fmaxf(o5,0.f))<<16);
    q.w = (unsigned)f2bf(fmaxf(o6,0.f)) | ((unsigned)f2bf(fmaxf(o7,0.f))<<16);
    *(uint4*)(outb + (size_t)node*128 + cc) = q;
  }
}

// ------- output layer GEMM (bf16 in, 128->40 padded 64, bf16 H2 out) + fused logits -------
__global__ __launch_bounds__(256) void k_gemm40n(const unsigned short* __restrict__ Gb,
                                                 const float* __restrict__ Wt2p,
                                                 const float* __restrict__ as2,
                                                 const float* __restrict__ ad2,
                                                 unsigned short* __restrict__ H2b,
                                                 float* __restrict__ al2s,
                                                 float* __restrict__ al2d, int n){
  __shared__ float xt[128*68];   // xt[k*68 + r], r in [0,64)
  int tid = threadIdx.x;
  int r0 = blockIdx.x * 64;
  {
    int r  = tid & 63;
    int c0 = (tid >> 6) * 32;
    int row = r0 + r;
    #pragma unroll
    for (int j=0;j<4;++j){
      uint4 v = (row < n) ? *(const uint4*)(Gb + (size_t)row*128 + c0 + j*8)
                          : make_uint4(0,0,0,0);
      int k = c0 + j*8;
      xt[(k+0)*68 + r] = bf_lo(v.x);  xt[(k+1)*68 + r] = bf_hi(v.x);
      xt[(k+2)*68 + r] = bf_lo(v.y);  xt[(k+3)*68 + r] = bf_hi(v.y);
      xt[(k+4)*68 + r] = bf_lo(v.z);  xt[(k+5)*68 + r] = bf_hi(v.z);
      xt[(k+6)*68 + r] = bf_lo(v.w);  xt[(k+7)*68 + r] = bf_hi(v.w);
    }
  }
  __syncthreads();
  int tc = tid & 15, tr = tid >> 4;
  float acc[4][4] = {};
  #pragma unroll 4
  for (int k=0;k<128;++k){
    float4 wv = *(const float4*)(Wt2p + k*64 + tc*4);
    float4 xv = *(const float4*)(&xt[k*68 + tr*4]);
    float xv4[4] = {xv.x, xv.y, xv.z, xv.w};
    float wv4[4] = {wv.x, wv.y, wv.z, wv.w};
    #pragma unroll
    for (int u=0;u<4;++u)
      #pragma unroll
      for (int v=0;v<4;++v)
        acc[u][v] = fmaf(xv4[u], wv4[v], acc[u][v]);
  }
  float4 a4 = make_float4(0.f,0.f,0.f,0.f), d4 = a4;
  if (tc < 10){
    a4 = *(const float4*)(as2 + tc*4);
    d4 = *(const float4*)(ad2 + tc*4);
  }
  #pragma unroll
  for (int u=0;u<4;++u){
    int row = r0 + tr*4 + u;
    float ps = acc[u][0]*a4.x + acc[u][1]*a4.y + acc[u][2]*a4.z + acc[u][3]*a4.w;
    float pd = acc[u][0]*d4.x + acc[u][1]*d4.y + acc[u][2]*d4.z + acc[u][3]*d4.w;
    #pragma unroll
    for (int m=1; m<16; m<<=1){ ps += __shfl_xor(ps,m); pd += __shfl_xor(pd,m); }
    if (row < n){
      if (tc < 10){
        ushort4 o;
        o.x = f2bf(acc[u][0]); o.y = f2bf(acc[u][1]);
        o.z = f2bf(acc[u][2]); o.w = f2bf(acc[u][3]);
        *(ushort4*)(H2b + (size_t)row*40 + tc*4) = o;
      }
      if (tc == 0){ al2s[row] = ps; al2d[row] = pd; }
    }
  }
}

// ------- output aggregation + bias + log_softmax (8 edges/step, upfront weights, prefetch) -------
__global__ __launch_bounds__(256) void k_agg40b(const unsigned short* __restrict__ H2b,
                        const float* __restrict__ ALs, const float* __restrict__ ALd,
                        const int* __restrict__ offs, const int* __restrict__ csr,
                        const float* __restrict__ b2, float* __restrict__ out, int n){
  int node = blockIdx.x*4 + (threadIdx.x >> 6);
  int lane = threadIdx.x & 63;
  if (node >= n) return;
  int el = lane >> 3, fl = lane & 7;
  bool act = fl < 5;
  int beg = offs[node], end = offs[node+1];
  int deg = end - beg;
  float ald = ALd[node];
  int c = (lane < deg) ? csr[beg + lane] : 0;
  // upfront weights for the preloaded 64 edges: lane's own edge
  float wch = (lane < deg) ? __expf(lrelu(ALs[c] + ald)) : 0.f;
  float a0=0.f,a1=0.f,a2=0.f,a3=0.f,a4=0.f,a5=0.f,a6=0.f,a7=0.f;
  float wsum = 0.f;
  int nsteps = (deg + 7) >> 3;
  int ns64 = min(nsteps, 8);
  uint4 hv = make_uint4(0,0,0,0);
  {
    int si = __shfl(c, el);
    if (act) hv = *(const uint4*)(H2b + (size_t)si*40 + fl*8);
  }
  for (int st = 0; st < ns64; ++st){
    float w = __shfl(wch, st*8 + el);
    uint4 hvN = make_uint4(0,0,0,0);
    if (st + 1 < ns64){
      int siN = __shfl(c, (st+1)*8 + el);
      if (act) hvN = *(const uint4*)(H2b + (size_t)siN*40 + fl*8);
    }
    wsum += w;
    a0 = fmaf(w, bf_lo(hv.x), a0);  a1 = fmaf(w, bf_hi(hv.x), a1);
    a2 = fmaf(w, bf_lo(hv.y), a2);  a3 = fmaf(w, bf_hi(hv.y), a3);
    a4 = fmaf(w, bf_lo(hv.z), a4);  a5 = fmaf(w, bf_hi(hv.z), a5);
    a6 = fmaf(w, bf_lo(hv.w), a6);  a7 = fmaf(w, bf_hi(hv.w), a7);
    hv = hvN;
  }
  if (deg > 64){
    for (int idx = 64 + el; idx < deg; idx += 8){
      int si = csr[beg + idx];
      float w = __expf(lrelu(ALs[si] + ald));
      wsum += w;
      if (act){
        uint4 h4 = *(const uint4*)(H2b + (size_t)si*40 + fl*8);
        a0 = fmaf(w, bf_lo(h4.x), a0);  a1 = fmaf(w, bf_hi(h4.x), a1);
        a2 = fmaf(w, bf_lo(h4.y), a2);  a3 = fmaf(w, bf_hi(h4.y), a3);
        a4 = fmaf(w, bf_lo(h4.z), a4);  a5 = fmaf(w, bf_hi(h4.z), a5);
        a6 = fmaf(w, bf_lo(h4.w), a6);  a7 = fmaf(w, bf_hi(h4.w), a7);
      }
    }
  }
  #pragma unroll
  for (int off=8; off<64; off<<=1){
    a0 += __shfl_xor(a0, off); a1 += __shfl_xor(a1, off);
    a2 += __shfl_xor(a2, off); a3 += __shfl_xor(a3, off);
    a4 += __shfl_xor(a4, off); a5 += __shfl_xor(a5, off);
    a6 += __shfl_xor(a6, off); a7 += __shfl_xor(a7, off);
    wsum += __shfl_xor(wsum, off);
  }
  if (el == 0){
    float inv = 1.f / wsum;
    float y0=0.f,y1=0.f,y2=0.f,y3=0.f,y4=0.f,y5=0.f,y6=0.f,y7=0.f;
    if (act){
      int cc = fl*8;
      float4 bA = *(const float4*)(b2 + cc), bB = *(const float4*)(b2 + cc + 4);
      y0 = a0*inv + bA.x; y1 = a1*inv + bA.y; y2 = a2*inv + bA.z; y3 = a3*inv + bA.w;
      y4 = a4*inv + bB.x; y5 = a5*inv + bB.y; y6 = a6*inv + bB.z; y7 = a7*inv + bB.w;
    }
    float lm = act ? fmaxf(fmaxf(fmaxf(y0,y1),fmaxf(y2,y3)),
                           fmaxf(fmaxf(y4,y5),fmaxf(y6,y7))) : -1e30f;
    lm = fmaxf(lm, __shfl_xor(lm,1));
    lm = fmaxf(lm, __shfl_xor(lm,2));
    lm = fmaxf(lm, __shfl_xor(lm,4));
    float ls = act ? (__expf(y0-lm)+__expf(y1-lm)+__expf(y2-lm)+__expf(y3-lm)
                     +__expf(y4-lm)+__expf(y5-lm)+__expf(y6-lm)+__expf(y7-lm)) : 0.f;
    ls += __shfl_xor(ls,1);
    ls += __shfl_xor(ls,2);
    ls += __shfl_xor(ls,4);
    float lg = lm + __logf(ls);
    if (act){
      float4* dst = (float4*)(out + (size_t)node*40 + fl*8);
      dst[0] = make_float4(y0-lg, y1-lg, y2-lg, y3-lg);
      dst[1] = make_float4(y4-lg, y5-lg, y6-lg, y7-lg);
    }
  }
}

extern "C" void kernel_launch(void* const* d_in, const int* in_sizes, int n_in,
                              void* d_out, int out_size, void* d_ws, size_t ws_size,
                              hipStream_t stream) {
  const float* x   = (const float*)d_in[0];
  const int*   ei  = (const int*)d_in[1];
  const float* W0  = (const float*)d_in[2];
  const float* as0 = (const float*)d_in[3];
  const float* ad0 = (const float*)d_in[4];
  const float* b0  = (const float*)d_in[5];
  const float* g0  = (const float*)d_in[6];
  const float* be0 = (const float*)d_in[7];
  const float* m0  = (const float*)d_in[8];
  const float* v0  = (const float*)d_in[9];
  const float* W1  = (const float*)d_in[10];
  const float* as1 = (const float*)d_in[11];
  const float* ad1 = (const float*)d_in[12];
  const float* b1  = (const float*)d_in[13];
  const float* g1  = (const float*)d_in[14];
  const float* be1 = (const float*)d_in[15];
  const float* m1  = (const float*)d_in[16];
  const float* v1  = (const float*)d_in[17];
  const float* W2  = (const float*)d_in[18];
  const float* as2 = (const float*)d_in[19];
  const float* ad2 = (const float*)d_in[20];
  const float* b2  = (const float*)d_in[21];
  float* out = (float*)d_out;

  int N = in_sizes[0] / 128;
  int E = in_sizes[1] / 2;
  int ET = E + N;
  int NBIN = (N + SNODES - 1) >> SBITS;   // 196 for N=100000 (<= NBIN_MAX)
  int M = NBIN * GLH;                     // Hmat/Bmat length (~50K)

  char* p = (char*)d_ws;
  auto alloc = [&](size_t bytes)->void* {
    void* r = (void*)p;
    p += (bytes + 255) & ~size_t(255);
    return r;
  };
  unsigned short* Wb0 = (unsigned short*)alloc((size_t)128*128*2);
  unsigned short* Wb1 = (unsigned short*)alloc((size_t)128*128*2);
  float* Wt2p  = (float*)alloc((size_t)128*64*4);
  int* offs    = (int*)alloc((size_t)(N+1)*4);
  int* partials= (int*)alloc(1024*4);
  int* Hmat    = (int*)alloc((size_t)NBIN_MAX*GLH*4);
  int* Bmat    = (int*)alloc((size_t)(NBIN_MAX*GLH+1)*4);
  int* csr     = (int*)alloc((size_t)ET*4);
  unsigned* staged = (unsigned*)alloc((size_t)ET*4);
  unsigned short* Pb = (unsigned short*)alloc((size_t)N*128*2);
  unsigned short* Gb = (unsigned short*)alloc((size_t)N*128*2);
  float* ALs = (float*)alloc((size_t)N*4*4);
  float* ALd = (float*)alloc((size_t)N*4*4);
  unsigned short* H2b = Pb;     // Pb free by the time layer-2 GEMM runs
  float* al2s = ALs;
  float* al2d = ALd;
  if ((size_t)(p - (char*)d_ws) > ws_size) return;  // workspace too small

  // weight prep (one kernel: W0,W1 -> bf16; W2 -> padded transpose)
  k_prep<<<(40960+255)/256, 256, 0, stream>>>(W0, W1, W2, Wb0, Wb1, Wt2p);

  // ---- CSR build: local hists -> Bmat scan -> bucketed write -> per-bucket offs+csr ----
  k_lhist<<<GLH, 256, 0, stream>>>(ei, E, N, Hmat, NBIN);
  int nb2 = (M + 1023) / 1024;
  k_scan1<<<nb2, 256, 0, stream>>>(Hmat, Bmat+1, partials, M);
  k_scan2<<<1, 256, 0, stream>>>(partials, nb2);
  k_scan3<<<(M+255)/256, 256, 0, stream>>>(Bmat, partials, M);
  k_write<<<GLH, 256, 0, stream>>>(ei, E, N, Bmat, staged, NBIN);
  k_bucket3<<<NBIN, 256, 0, stream>>>(staged, Bmat, offs, csr, N, ET);

  int gb = (N + 63) / 64;
  // ---- layer 0 ----
  k_gemm128m<false><<<gb, 256, 0, stream>>>(x, Wb0, as0, ad0, Pb, ALs, ALd, N);
  k_agg128b<<<(N+3)/4, 256, 0, stream>>>(Pb, ALs, ALd, offs, csr, b0, g0, be0, m0, v0, Gb, N);

  // ---- layer 1 ----
  k_gemm128m<true><<<gb, 256, 0, stream>>>(Gb, Wb1, as1, ad1, Pb, ALs, ALd, N);
  k_agg128b<<<(N+3)/4, 256, 0, stream>>>(Pb, ALs, ALd, offs, csr, b1, g1, be1, m1, v1, Gb, N);

  // ---- output layer ----
  k_gemm40n<<<gb, 256, 0, stream>>>(Gb, Wt2p, as2, ad2, H2b, al2s, al2d, N);
  k_agg40b<<<(N+3)/4, 256, 0, stream>>>(H2b, al2s, al2d, offs, csr, b2, out, N);
}

// Round 10
// 475.411 us; speedup vs baseline: 4.0068x; 1.0129x over previous
//
#include <hip/hip_runtime.h>
#include <math.h>

#define NEGS 0.2f
#define EPSBN 1e-5f
#define NBIN_MAX 256
#define SBITS 9
#define SNODES 512
#define GLH 256   // blocks for lhist/write

typedef __attribute__((ext_vector_type(8))) short short8v;   // 8 bf16 = 4 VGPR
typedef __attribute__((ext_vector_type(4))) float f32x4;     // MFMA acc
typedef __attribute__((ext_vector_type(2))) float f32x2;     // packed f32 (v_pk_fma_f32)

static __device__ __forceinline__ float lrelu(float x){ return x > 0.f ? x : NEGS*x; }
static __device__ __forceinline__ float bf_lo(unsigned u){ return __uint_as_float(u << 16); }
static __device__ __forceinline__ float bf_hi(unsigned u){ return __uint_as_float(u & 0xffff0000u); }
static __device__ __forceinline__ float bf1(unsigned short v){ return __uint_as_float(((unsigned)v) << 16); }
static __device__ __forceinline__ unsigned short f2bf(float f){
  unsigned u = __float_as_uint(f);
  unsigned r = (u + 0x7fff + ((u >> 16) & 1)) >> 16;   // RNE
  return (unsigned short)r;
}

// ---- combined: blocks [0,GLH) = bucket histogram; blocks >= GLH = weight prep ----
__global__ __launch_bounds__(256) void k_lhist_prep(const int* __restrict__ ei, int E, int N,
                       int* __restrict__ Hmat, int nbin,
                       const float* __restrict__ W0, const float* __restrict__ W1,
                       const float* __restrict__ W2, unsigned short* __restrict__ Wb0,
                       unsigned short* __restrict__ Wb1, float* __restrict__ Wt2p){
  if (blockIdx.x >= GLH){
    int i = (blockIdx.x - GLH)*256 + threadIdx.x;
    if (i < 16384){ Wb0[i] = f2bf(W0[i]); return; }
    if (i < 32768){ Wb1[i-16384] = f2bf(W1[i-16384]); return; }
    if (i < 40960){
      int j = i - 32768;
      int k = j >> 6, c = j & 63;
      Wt2p[j] = (c < 40) ? W2[c*128 + k] : 0.f;
    }
    return;
  }
  __shared__ int lh[NBIN_MAX];
  int tid = threadIdx.x;
  lh[tid] = 0;
  __syncthreads();
  int ET = E + N;
  int c0 = (int)(((long long)ET * blockIdx.x) / GLH);
  int c1 = (int)(((long long)ET * (blockIdx.x+1)) / GLH);
  for (int i = c0 + tid; i < c1; i += 256){
    int d = (i < E) ? ei[E + i] : (i - E);
    atomicAdd(&lh[d >> SBITS], 1);
  }
  __syncthreads();
  for (int b = tid; b < nbin; b += 256)
    Hmat[b*GLH + blockIdx.x] = lh[b];
}

// generic 3-kernel exclusive scan (scan1 writes inclusive into incl[i] = out[i+1])
__global__ void k_scan1(const int* __restrict__ in, int* __restrict__ incl,
                        int* __restrict__ partials, int n){
  __shared__ int sd[256];
  int tid = threadIdx.x;
  int base = blockIdx.x*1024 + tid*4;
  int v[4]; int s = 0;
  #pragma unroll
  for (int j=0;j<4;++j){ int idx = base+j; v[j] = (idx<n)? in[idx] : 0; s += v[j]; }
  sd[tid] = s; __syncthreads();
  for (int off=1; off<256; off<<=1){
    int t = (tid>=off)? sd[tid-off] : 0;
    __syncthreads();
    sd[tid] += t;
    __syncthreads();
  }
  int run = sd[tid] - s;
  #pragma unroll
  for (int j=0;j<4;++j){ int idx = base+j; run += v[j]; if (idx<n) incl[idx] = run; }
  if (tid==255) partials[blockIdx.x] = sd[255];
}

__global__ void k_scan2(int* partials, int nb){
  __shared__ int sd[256];
  int tid = threadIdx.x;
  sd[tid] = (tid<nb)? partials[tid] : 0;
  __syncthreads();
  for (int off=1; off<256; off<<=1){
    int t = (tid>=off)? sd[tid-off] : 0;
    __syncthreads();
    sd[tid] += t;
    __syncthreads();
  }
  if (tid<nb) partials[tid] = sd[tid];
}

__global__ void k_scan3(int* __restrict__ offs, const int* __restrict__ partials, int n){
  int i = blockIdx.x*256 + threadIdx.x;
  if (i == 0) offs[0] = 0;
  if (i >= n) return;
  int b = i >> 10;
  if (b > 0) offs[i+1] += partials[b-1];
}

// write packed (dlocal<<23)|src into disjoint staged ranges (LDS cursors)
__global__ __launch_bounds__(256) void k_write(const int* __restrict__ ei, int E, int N,
                        const int* __restrict__ Bmat, unsigned* __restrict__ staged, int nbin){
  __shared__ int cur[NBIN_MAX];
  int tid = threadIdx.x;
  for (int b = tid; b < nbin; b += 256)
    cur[b] = Bmat[b*GLH + blockIdx.x];
  __syncthreads();
  int ET = E + N;
  int c0 = (int)(((long long)ET * blockIdx.x) / GLH);
  int c1 = (int)(((long long)ET * (blockIdx.x+1)) / GLH);
  for (int i = c0 + tid; i < c1; i += 256){
    int s, d;
    if (i < E){ s = ei[i]; d = ei[E+i]; } else { s = i-E; d = i-E; }
    int pos = atomicAdd(&cur[d >> SBITS], 1);
    staged[pos] = (unsigned)s | ((unsigned)(d & (SNODES-1)) << 23);
  }
}

// one block per bucket: per-node degree + LDS scan -> offs, then csr scatter
__global__ __launch_bounds__(256) void k_bucket3(const unsigned* __restrict__ staged,
                         const int* __restrict__ Bmat,
                         int* __restrict__ offs, int* __restrict__ csr, int N, int ET){
  __shared__ int sdeg[SNODES];
  __shared__ int sexc[SNODES];
  int b = blockIdx.x, tid = threadIdx.x;
  int node0 = b << SBITS;
  int nn = min(SNODES, N - node0);
  int base = Bmat[b*GLH];
  int cntb = Bmat[(b+1)*GLH] - base;
  sdeg[2*tid] = 0; sdeg[2*tid+1] = 0;
  __syncthreads();
  for (int e = tid; e < cntb; e += 256){
    unsigned p = staged[base + e];
    atomicAdd(&sdeg[p >> 23], 1);
  }
  __syncthreads();
  int v0 = sdeg[2*tid], v1 = sdeg[2*tid+1];
  int ps = v0 + v1;
  sexc[tid] = ps; __syncthreads();
  for (int off=1; off<256; off<<=1){
    int t = (tid>=off)? sexc[tid-off] : 0;
    __syncthreads();
    sexc[tid] += t;
    __syncthreads();
  }
  int excl_pair = sexc[tid] - ps;
  __syncthreads();
  sexc[2*tid]   = excl_pair;
  sexc[2*tid+1] = excl_pair + v0;
  if (2*tid   < nn) offs[node0 + 2*tid]   = base + excl_pair;
  if (2*tid+1 < nn) offs[node0 + 2*tid+1] = base + excl_pair + v0;
  sdeg[2*tid] = 0; sdeg[2*tid+1] = 0;
  __syncthreads();
  for (int e = tid; e < cntb; e += 256){
    unsigned p = staged[base + e];
    int ln = p >> 23;
    int pos = base + sexc[ln] + atomicAdd(&sdeg[ln], 1);
    csr[pos] = (int)(p & 0x7FFFFFu);
  }
  if (b == gridDim.x - 1 && tid == 0) offs[N] = ET;
}

// ------- MFMA GEMM 128x128 (X f32 or bf16 in, W pre-converted bf16, bf16 out) + fused logits -------
template<bool BF16IN>
__global__ __launch_bounds__(256) void k_gemm128m(const void* __restrict__ Xin,
                          const unsigned short* __restrict__ Wb,
                          const float* __restrict__ as_, const float* __restrict__ ad_,
                          unsigned short* __restrict__ Yb,
                          float* __restrict__ ALs, float* __restrict__ ALd, int n){
  __shared__ short lds[24576];               // Wb 128x128 @0 (32KB), Xb 64x128 @16384 (16KB)
  unsigned* ldsW = (unsigned*)lds;           // 8192 dwords
  unsigned* ldsX = (unsigned*)(lds + 16384); // 4096 dwords
  int tid = threadIdx.x;
  int r0 = blockIdx.x*64;
  // stage W (bf16, swizzled): 8 x uint4 per thread
  #pragma unroll
  for (int j=0;j<8;++j){
    int dw4 = 1024*j + tid*4;
    int row = dw4 >> 6;
    uint4 v = *(const uint4*)(Wb + (size_t)dw4*2);
    int lo = dw4 & 63, base = dw4 & ~63;
    *(uint4*)(&ldsW[base | (lo ^ ((row&7)<<2))]) = v;
  }
  if (!BF16IN){
    const float* X = (const float*)Xin;
    #pragma unroll
    for (int j=0;j<8;++j){
      int i = (256*j + tid)*4;
      int row = i >> 7;
      int grow = r0 + row;
      float4 v = (grow < n) ? *(const float4*)(X + (size_t)grow*128 + (i&127))
                            : make_float4(0.f,0.f,0.f,0.f);
      int dw = i >> 1, lo = dw & 63, base = dw & ~63;
      int sw = base | (lo ^ ((row&7)<<2));
      uint2 p;
      p.x = (unsigned)f2bf(v.x) | ((unsigned)f2bf(v.y)<<16);
      p.y = (unsigned)f2bf(v.z) | ((unsigned)f2bf(v.w)<<16);
      *(uint2*)(&ldsX[sw]) = p;
    }
  } else {
    const unsigned short* Xb = (const unsigned short*)Xin;
    #pragma unroll
    for (int j=0;j<4;++j){
      int dw4 = 1024*j + tid*4;
      int row = dw4 >> 6;
      int grow = r0 + row;
      uint4 v = (grow < n) ? *(const uint4*)(Xb + (size_t)grow*128 + (dw4&63)*2)
                           : make_uint4(0,0,0,0);
      int lo = dw4 & 63, base = dw4 & ~63;
      int sw = base | (lo ^ ((row&7)<<2));
      *(uint4*)(&ldsX[sw]) = v;
    }
  }
  __syncthreads();
  int l = tid & 63, w = tid >> 6;
  int lrow = l & 15, lk = l >> 4;
  int arow = w*16 + lrow;
  int abase = arow*64, ax = (arow&7)<<2;
  short8v a[4];
  #pragma unroll
  for (int ks=0;ks<4;++ks){
    int lo = ks*16 + lk*4;
    a[ks] = *(const short8v*)&ldsX[abase + (lo ^ ax)];
  }
  f32x4 acc[8];
  #pragma unroll
  for (int c=0;c<8;++c) acc[c] = (f32x4){0.f,0.f,0.f,0.f};
  #pragma unroll
  for (int c=0;c<8;++c){
    int brow = c*16 + lrow;
    int bbase2 = brow*64, bx = (brow&7)<<2;
    #pragma unroll
    for (int ks=0;ks<4;++ks){
      int lo = ks*16 + lk*4;
      short8v bfr = *(const short8v*)&ldsW[bbase2 + (lo ^ bx)];
      acc[c] = __builtin_amdgcn_mfma_f32_16x16x32_bf16(a[ks], bfr, acc[c], 0, 0, 0);
    }
  }
  __syncthreads();
  unsigned short* Ys = (unsigned short*)ldsX;
  #pragma unroll
  for (int c=0;c<8;++c){
    #pragma unroll
    for (int r=0;r<4;++r){
      int row = w*16 + lk*4 + r;
      Ys[row*128 + c*16 + lrow] = f2bf(acc[c][r]);
    }
  }
  __syncthreads();
  #pragma unroll
  for (int j=0;j<4;++j){
    int dw4 = 1024*j + tid*4;
    int row = dw4 >> 6;
    int grow = r0 + row;
    if (grow < n)
      *(uint4*)(Yb + (size_t)grow*128 + (dw4&63)*2) = *(const uint4*)&((unsigned*)ldsX)[dw4];
  }
  {
    int row = tid >> 2, h = tid & 3;
    int grow = r0 + row;
    if (grow < n){
      const unsigned short* yr = Ys + row*128 + h*32;
      float ps = 0.f, pd = 0.f;
      #pragma unroll
      for (int j=0;j<32;++j){
        float y = bf1(yr[j]);
        ps = fmaf(y, as_[h*32+j], ps);
        pd = fmaf(y, ad_[h*32+j], pd);
      }
      ALs[grow*4+h] = ps; ALd[grow*4+h] = pd;
    }
  }
}

// ------- fused GAT aggregation + bias + BN + ReLU -------
// one wave per node; 4 edges/step, 16 lanes/edge. Upfront weights; fully
// unrolled MAC (wave-uniform break) with 2-deep prefetch and packed-f32 FMA.
__global__ __launch_bounds__(256) void k_agg128b(const unsigned short* __restrict__ Pb,
                         const float* __restrict__ ALs, const float* __restrict__ ALd,
                         const int* __restrict__ offs, const int* __restrict__ csr,
                         const float* __restrict__ bias, const float* __restrict__ gam,
                         const float* __restrict__ bet, const float* __restrict__ mean,
                         const float* __restrict__ var, unsigned short* __restrict__ outb, int n){
  int node = blockIdx.x*4 + (threadIdx.x >> 6);
  int lane = threadIdx.x & 63;
  if (node >= n) return;
  int el = lane >> 4, fl = lane & 15, hd = fl >> 2;
  int beg = offs[node], end = offs[node+1];
  int deg = end - beg;
  float aldw = ALd[node*4 + (lane & 3)];
  int c = (lane < deg) ? csr[beg + lane] : 0;   // preload up to 64 edge indices
  // upfront weights: lane handles edge (chunk*16 + lane>>2), head lane&3
  float w0, w1, w2, w3;
  {
    int e0 = lane >> 2, h0 = lane & 3;
    int s0 = __shfl(c, e0), s1 = __shfl(c, 16+e0);
    int s2 = __shfl(c, 32+e0), s3 = __shfl(c, 48+e0);
    float al0 = ALs[s0*4+h0], al1 = ALs[s1*4+h0];
    float al2 = ALs[s2*4+h0], al3 = ALs[s3*4+h0];
    w0 = (e0      < deg) ? __expf(lrelu(al0 + aldw)) : 0.f;
    w1 = (16 + e0 < deg) ? __expf(lrelu(al1 + aldw)) : 0.f;
    w2 = (32 + e0 < deg) ? __expf(lrelu(al2 + aldw)) : 0.f;
    w3 = (48 + e0 < deg) ? __expf(lrelu(al3 + aldw)) : 0.f;
  }
  f32x2 A0 = (f32x2){0.f,0.f}, A1 = A0, A2 = A0, A3 = A0;
  float wsum = 0.f;
  int nsteps = (deg + 3) >> 2;
  int ns64 = min(nsteps, 16);
  // 2-deep rotating prefetch (static names, no dynamic indexing)
  uint4 p0, p1;
  {
    int s0i = __shfl(c, el);
    p0 = *(const uint4*)(Pb + (size_t)s0i*128 + fl*8);
  }
  if (ns64 > 1){
    int s1i = __shfl(c, 4 + el);
    p1 = *(const uint4*)(Pb + (size_t)s1i*128 + fl*8);
  } else p1 = make_uint4(0,0,0,0);
  #pragma unroll
  for (int st = 0; st < 16; ++st){
    if (st >= ns64) break;
    uint4 cur = (st & 1) ? p1 : p0;          // compile-time select (unrolled)
    float wc = (st>>2)==0 ? w0 : (st>>2)==1 ? w1 : (st>>2)==2 ? w2 : w3;
    float w = __shfl(wc, ((st&3)*4 + el)*4 + hd);
    uint4 nxt = make_uint4(0,0,0,0);
    if (st + 2 < ns64){
      int sN = __shfl(c, (st+2)*4 + el);
      nxt = *(const uint4*)(Pb + (size_t)sN*128 + fl*8);
    }
    wsum += w;
    f32x2 wv = (f32x2){w, w};
    A0 += (f32x2){bf_lo(cur.x), bf_hi(cur.x)} * wv;
    A1 += (f32x2){bf_lo(cur.y), bf_hi(cur.y)} * wv;
    A2 += (f32x2){bf_lo(cur.z), bf_hi(cur.z)} * wv;
    A3 += (f32x2){bf_lo(cur.w), bf_hi(cur.w)} * wv;
    if (st & 1) p1 = nxt; else p0 = nxt;
  }
  float a0=A0.x, a1=A0.y, a2=A1.x, a3=A1.y, a4=A2.x, a5=A2.y, a6=A3.x, a7=A3.y;
  // tail for deg > 64 (rare): inline exp per edge-group
  if (deg > 64){
    float aldh = __shfl(aldw, hd);
    for (int idx = 64 + el; idx < deg; idx += 4){
      int si = csr[beg + idx];
      float w = __expf(lrelu(ALs[si*4 + hd] + aldh));
      uint4 h4 = *(const uint4*)(Pb + (size_t)si*128 + fl*8);
      wsum += w;
      a0 = fmaf(w, bf_lo(h4.x), a0);  a1 = fmaf(w, bf_hi(h4.x), a1);
      a2 = fmaf(w, bf_lo(h4.y), a2);  a3 = fmaf(w, bf_hi(h4.y), a3);
      a4 = fmaf(w, bf_lo(h4.z), a4);  a5 = fmaf(w, bf_hi(h4.z), a5);
      a6 = fmaf(w, bf_lo(h4.w), a6);  a7 = fmaf(w, bf_hi(h4.w), a7);
    }
  }
  #pragma unroll
  for (int off=16; off<64; off<<=1){
    a0 += __shfl_xor(a0, off); a1 += __shfl_xor(a1, off);
    a2 += __shfl_xor(a2, off); a3 += __shfl_xor(a3, off);
    a4 += __shfl_xor(a4, off); a5 += __shfl_xor(a5, off);
    a6 += __shfl_xor(a6, off); a7 += __shfl_xor(a7, off);
    wsum += __shfl_xor(wsum, off);
  }
  if (el == 0){
    float inv = 1.f / wsum;
    int cc = fl*8;
    float4 bA = *(const float4*)(bias+cc), bB = *(const float4*)(bias+cc+4);
    float4 gA = *(const float4*)(gam+cc),  gB = *(const float4*)(gam+cc+4);
    float4 eA = *(const float4*)(bet+cc),  eB = *(const float4*)(bet+cc+4);
    float4 uA = *(const float4*)(mean+cc), uB = *(const float4*)(mean+cc+4);
    float4 vA = *(const float4*)(var+cc),  vB = *(const float4*)(var+cc+4);
    float o0 = (a0*inv + bA.x - uA.x) * rsqrtf(vA.x + EPSBN) * gA.x + eA.x;
    float o1 = (a1*inv + bA.y - uA.y) * rsqrtf(vA.y + EPSBN) * gA.y + eA.y;
    float o2 = (a2*inv + bA.z - uA.z) * rsqrtf(vA.z + EPSBN) * gA.z + eA.z;
    float o3 = (a3*inv + bA.w - uA.w) * rsqrtf(vA.w + EPSBN) * gA.w + eA.w;
    float o4 = (a4*inv + bB.x - uB.x) * rsqrtf(vB.x + EPSBN) * gB.x + eB.x;
    float o5 = (a5*inv + bB.y - uB.y) * rsqrtf(vB.y + EPSBN) * gB.y + eB.y;
    float o6 = (a6*inv + bB.z - uB.z) * rsqrtf(vB.z + EPSBN) * gB.z + eB.z;
    float o7 = (a7*inv + bB.w - uB.w) * rsqrtf(vB.w + EPSBN) * gB.w + eB.w;
    uint4 q;
    q.x = (unsigned)f2bf(fmaxf(o0,0.f)) | ((unsigned)f2bf(fmaxf(o1,0.f))<<16);
    q.y = (unsigned)f2bf(fmaxf(o2,0.f)) | ((unsigned)f2bf(fmaxf(o3,0.f))<<16);
    q.z = (unsigned)f2bf(fmaxf(o4,0.f)) | ((unsigned)f2bf(fmaxf(o5,0.f))<<16);
    q.w = (unsigned)f2bf(fmaxf(o6,0.f)) | ((unsigned)f2bf(fmaxf(o7,0.f))<<16);
    *(uint4*)(outb + (size_t)node*128 + cc) = q;
  }
}

// ------- output layer GEMM (bf16 in, 128->40 padded 64, bf16 H2 out) + fused logits -------
__global__ __launch_bounds__(256) void k_gemm40n(const unsigned short* __restrict__ Gb,
                                                 const float* __restrict__ Wt2p,
                                                 const float* __restrict__ as2,
                                                 const float* __restrict__ ad2,
                                                 unsigned short* __restrict__ H2b,
                                                 float* __restrict__ al2s,
                                                 float* __restrict__ al2d, int n){
  __shared__ float xt[128*68];   // xt[k*68 + r], r in [0,64)
  int tid = threadIdx.x;
  int r0 = blockIdx.x * 64;
  {
    int r  = tid & 63;
    int c0 = (tid >> 6) * 32;
    int row = r0 + r;
    #pragma unroll
    for (int j=0;j<4;++j){
      uint4 v = (row < n) ? *(const uint4*)(Gb + (size_t)row*128 + c0 + j*8)
                          : make_uint4(0,0,0,0);
      int k = c0 + j*8;
      xt[(k+0)*68 + r] = bf_lo(v.x);  xt[(k+1)*68 + r] = bf_hi(v.x);
      xt[(k+2)*68 + r] = bf_lo(v.y);  xt[(k+3)*68 + r] = bf_hi(v.y);
      xt[(k+4)*68 + r] = bf_lo(v.z);  xt[(k+5)*68 + r] = bf_hi(v.z);
      xt[(k+6)*68 + r] = bf_lo(v.w);  xt[(k+7)*68 + r] = bf_hi(v.w);
    }
  }
  __syncthreads();
  int tc = tid & 15, tr = tid >> 4;
  float acc[4][4] = {};
  #pragma unroll 4
  for (int k=0;k<128;++k){
    float4 wv = *(const float4*)(Wt2p + k*64 + tc*4);
    float4 xv = *(const float4*)(&xt[k*68 + tr*4]);
    float xv4[4] = {xv.x, xv.y, xv.z, xv.w};
    float wv4[4] = {wv.x, wv.y, wv.z, wv.w};
    #pragma unroll
    for (int u=0;u<4;++u)
      #pragma unroll
      for (int v=0;v<4;++v)
        acc[u][v] = fmaf(xv4[u], wv4[v], acc[u][v]);
  }
  float4 a4 = make_float4(0.f,0.f,0.f,0.f), d4 = a4;
  if (tc < 10){
    a4 = *(const float4*)(as2 + tc*4);
    d4 = *(const float4*)(ad2 + tc*4);
  }
  #pragma unroll
  for (int u=0;u<4;++u){
    int row = r0 + tr*4 + u;
    float ps = acc[u][0]*a4.x + acc[u][1]*a4.y + acc[u][2]*a4.z + acc[u][3]*a4.w;
    float pd = acc[u][0]*d4.x + acc[u][1]*d4.y + acc[u][2]*d4.z + acc[u][3]*d4.w;
    #pragma unroll
    for (int m=1; m<16; m<<=1){ ps += __shfl_xor(ps,m); pd += __shfl_xor(pd,m); }
    if (row < n){
      if (tc < 10){
        ushort4 o;
        o.x = f2bf(acc[u][0]); o.y = f2bf(acc[u][1]);
        o.z = f2bf(acc[u][2]); o.w = f2bf(acc[u][3]);
        *(ushort4*)(H2b + (size_t)row*40 + tc*4) = o;
      }
      if (tc == 0){ al2s[row] = ps; al2d[row] = pd; }
    }
  }
}

// ------- output aggregation + bias + log_softmax (8 edges/step, unrolled, packed FMA) -------
__global__ __launch_bounds__(256) void k_agg40b(const unsigned short* __restrict__ H2b,
                        const float* __restrict__ ALs, const float* __restrict__ ALd,
                        const int* __restrict__ offs, const int* __restrict__ csr,
                        const float* __restrict__ b2, float* __restrict__ out, int n){
  int node = blockIdx.x*4 + (threadIdx.x >> 6);
  int lane = threadIdx.x & 63;
  if (node >= n) return;
  int el = lane >> 3, fl = lane & 7;
  bool act = fl < 5;
  int beg = offs[node], end = offs[node+1];
  int deg = end - beg;
  float ald = ALd[node];
  int c = (lane < deg) ? csr[beg + lane] : 0;
  float wch = (lane < deg) ? __expf(lrelu(ALs[c] + ald)) : 0.f;
  f32x2 A0 = (f32x2){0.f,0.f}, A1 = A0, A2 = A0, A3 = A0;
  float wsum = 0.f;
  int nsteps = (deg + 7) >> 3;
  int ns64 = min(nsteps, 8);
  uint4 p0 = make_uint4(0,0,0,0), p1 = p0;
  {
    int si = __shfl(c, el);
    if (act) p0 = *(const uint4*)(H2b + (size_t)si*40 + fl*8);
  }
  if (ns64 > 1){
    int si = __shfl(c, 8 + el);
    if (act) p1 = *(const uint4*)(H2b + (size_t)si*40 + fl*8);
  }
  #pragma unroll
  for (int st = 0; st < 8; ++st){
    if (st >= ns64) break;
    uint4 cur = (st & 1) ? p1 : p0;
    float w = __shfl(wch, st*8 + el);
    uint4 nxt = make_uint4(0,0,0,0);
    if (st + 2 < ns64){
      int sN = __shfl(c, (st+2)*8 + el);
      if (act) nxt = *(const uint4*)(H2b + (size_t)sN*40 + fl*8);
    }
    wsum += w;
    f32x2 wv = (f32x2){w, w};
    A0 += (f32x2){bf_lo(cur.x), bf_hi(cur.x)} * wv;
    A1 += (f32x2){bf_lo(cur.y), bf_hi(cur.y)} * wv;
    A2 += (f32x2){bf_lo(cur.z), bf_hi(cur.z)} * wv;
    A3 += (f32x2){bf_lo(cur.w), bf_hi(cur.w)} * wv;
    if (st & 1) p1 = nxt; else p0 = nxt;
  }
  float a0=A0.x, a1=A0.y, a2=A1.x, a3=A1.y, a4=A2.x, a5=A2.y, a6=A3.x, a7=A3.y;
  if (deg > 64){
    for (int idx = 64 + el; idx < deg; idx += 8){
      int si = csr[beg + idx];
      float w = __expf(lrelu(ALs[si] + ald));
      wsum += w;
      if (act){
        uint4 h4 = *(const uint4*)(H2b + (size_t)si*40 + fl*8);
        a0 = fmaf(w, bf_lo(h4.x), a0);  a1 = fmaf(w, bf_hi(h4.x), a1);
        a2 = fmaf(w, bf_lo(h4.y), a2);  a3 = fmaf(w, bf_hi(h4.y), a3);
        a4 = fmaf(w, bf_lo(h4.z), a4);  a5 = fmaf(w, bf_hi(h4.z), a5);
        a6 = fmaf(w, bf_lo(h4.w), a6);  a7 = fmaf(w, bf_hi(h4.w), a7);
      }
    }
  }
  #pragma unroll
  for (int off=8; off<64; off<<=1){
    a0 += __shfl_xor(a0, off); a1 += __shfl_xor(a1, off);
    a2 += __shfl_xor(a2, off); a3 += __shfl_xor(a3, off);
    a4 += __shfl_xor(a4, off); a5 += __shfl_xor(a5, off);
    a6 += __shfl_xor(a6, off); a7 += __shfl_xor(a7, off);
    wsum += __shfl_xor(wsum, off);
  }
  if (el == 0){
    float inv = 1.f / wsum;
    float y0=0.f,y1=0.f,y2=0.f,y3=0.f,y4=0.f,y5=0.f,y6=0.f,y7=0.f;
    if (act){
      int cc = fl*8;
      float4 bA = *(const float4*)(b2 + cc), bB = *(const float4*)(b2 + cc + 4);
      y0 = a0*inv + bA.x; y1 = a1*inv + bA.y; y2 = a2*inv + bA.z; y3 = a3*inv + bA.w;
      y4 = a4*inv + bB.x; y5 = a5*inv + bB.y; y6 = a6*inv + bB.z; y7 = a7*inv + bB.w;
    }
    float lm = act ? fmaxf(fmaxf(fmaxf(y0,y1),fmaxf(y2,y3)),
                           fmaxf(fmaxf(y4,y5),fmaxf(y6,y7))) : -1e30f;
    lm = fmaxf(lm, __shfl_xor(lm,1));
    lm = fmaxf(lm, __shfl_xor(lm,2));
    lm = fmaxf(lm, __shfl_xor(lm,4));
    float ls = act ? (__expf(y0-lm)+__expf(y1-lm)+__expf(y2-lm)+__expf(y3-lm)
                     +__expf(y4-lm)+__expf(y5-lm)+__expf(y6-lm)+__expf(y7-lm)) : 0.f;
    ls += __shfl_xor(ls,1);
    ls += __shfl_xor(ls,2);
    ls += __shfl_xor(ls,4);
    float lg = lm + __logf(ls);
    if (act){
      float4* dst = (float4*)(out + (size_t)node*40 + fl*8);
      dst[0] = make_float4(y0-lg, y1-lg, y2-lg, y3-lg);
      dst[1] = make_float4(y4-lg, y5-lg, y6-lg, y7-lg);
    }
  }
}

extern "C" void kernel_launch(void* const* d_in, const int* in_sizes, int n_in,
                              void* d_out, int out_size, void* d_ws, size_t ws_size,
                              hipStream_t stream) {
  const float* x   = (const float*)d_in[0];
  const int*   ei  = (const int*)d_in[1];
  const float* W0  = (const float*)d_in[2];
  const float* as0 = (const float*)d_in[3];
  const float* ad0 = (const float*)d_in[4];
  const float* b0  = (const float*)d_in[5];
  const float* g0  = (const float*)d_in[6];
  const float* be0 = (const float*)d_in[7];
  const float* m0  = (const float*)d_in[8];
  const float* v0  = (const float*)d_in[9];
  const float* W1  = (const float*)d_in[10];
  const float* as1 = (const float*)d_in[11];
  const float* ad1 = (const float*)d_in[12];
  const float* b1  = (const float*)d_in[13];
  const float* g1  = (const float*)d_in[14];
  const float* be1 = (const float*)d_in[15];
  const float* m1  = (const float*)d_in[16];
  const float* v1  = (const float*)d_in[17];
  const float* W2  = (const float*)d_in[18];
  const float* as2 = (const float*)d_in[19];
  const float* ad2 = (const float*)d_in[20];
  const float* b2  = (const float*)d_in[21];
  float* out = (float*)d_out;

  int N = in_sizes[0] / 128;
  int E = in_sizes[1] / 2;
  int ET = E + N;
  int NBIN = (N + SNODES - 1) >> SBITS;   // 196 for N=100000 (<= NBIN_MAX)
  int M = NBIN * GLH;                     // Hmat/Bmat length (~50K)

  char* p = (char*)d_ws;
  auto alloc = [&](size_t bytes)->void* {
    void* r = (void*)p;
    p += (bytes + 255) & ~size_t(255);
    return r;
  };
  unsigned short* Wb0 = (unsigned short*)alloc((size_t)128*128*2);
  unsigned short* Wb1 = (unsigned short*)alloc((size_t)128*128*2);
  float* Wt2p  = (float*)alloc((size_t)128*64*4);
  int* offs    = (int*)alloc((size_t)(N+1)*4);
  int* partials= (int*)alloc(1024*4);
  int* Hmat    = (int*)alloc((size_t)NBIN_MAX*GLH*4);
  int* Bmat    = (int*)alloc((size_t)(NBIN_MAX*GLH+1)*4);
  int* csr     = (int*)alloc((size_t)ET*4);
  unsigned* staged = (unsigned*)alloc((size_t)ET*4);
  unsigned short* Pb = (unsigned short*)alloc((size_t)N*128*2);
  unsigned short* Gb = (unsigned short*)alloc((size_t)N*128*2);
  float* ALs = (float*)alloc((size_t)N*4*4);
  float* ALd = (float*)alloc((size_t)N*4*4);
  unsigned short* H2b = Pb;     // Pb free by the time layer-2 GEMM runs
  float* al2s = ALs;
  float* al2d = ALd;
  if ((size_t)(p - (char*)d_ws) > ws_size) return;  // workspace too small

  // ---- CSR build + weight prep (merged first kernel) ----
  k_lhist_prep<<<GLH + 160, 256, 0, stream>>>(ei, E, N, Hmat, NBIN, W0, W1, W2, Wb0, Wb1, Wt2p);
  int nb2 = (M + 1023) / 1024;
  k_scan1<<<nb2, 256, 0, stream>>>(Hmat, Bmat+1, partials, M);
  k_scan2<<<1, 256, 0, stream>>>(partials, nb2);
  k_scan3<<<(M+255)/256, 256, 0, stream>>>(Bmat, partials, M);
  k_write<<<GLH, 256, 0, stream>>>(ei, E, N, Bmat, staged, NBIN);
  k_bucket3<<<NBIN, 256, 0, stream>>>(staged, Bmat, offs, csr, N, ET);

  int gb = (N + 63) / 64;
  // ---- layer 0 ----
  k_gemm128m<false><<<gb, 256, 0, stream>>>(x, Wb0, as0, ad0, Pb, ALs, ALd, N);
  k_agg128b<<<(N+3)/4, 256, 0, stream>>>(Pb, ALs, ALd, offs, csr, b0, g0, be0, m0, v0, Gb, N);

  // ---- layer 1 ----
  k_gemm128m<true><<<gb, 256, 0, stream>>>(Gb, Wb1, as1, ad1, Pb, ALs, ALd, N);
  k_agg128b<<<(N+3)/4, 256, 0, stream>>>(Pb, ALs, ALd, offs, csr, b1, g1, be1, m1, v1, Gb, N);

  // ---- output layer ----
  k_gemm40n<<<gb, 256, 0, stream>>>(Gb, Wt2p, as2, ad2, H2b, al2s, al2d, N);
  k_agg40b<<<(N+3)/4, 256, 0, stream>>>(H2b, al2s, al2d, offs, csr, b2, out, N);
}